// Round 1
// 2914.131 us; speedup vs baseline: 1.1825x; 1.1825x over previous
//
#include <hip/hip_runtime.h>
#include <math.h>

#define BB 8      // batch
#define KCH 10    // Chebyshev order
#define ROWS 64   // GEMM rows per block
#define GRD(n) ((int)(((n) + 255) / 256))

__device__ __forceinline__ float elu_f(float x){ return x > 0.f ? x : expf(x) - 1.f; }

// x input is [B, V] fp32 -> x0 [V, B] fp32
__global__ void transpose_in(const float* __restrict__ x, float* __restrict__ x0, int V){
  int i = blockIdx.x*256 + threadIdx.x;
  if (i < BB*V){
    int b = i / V, v = i - b*V;
    x0[(long)v*BB + b] = x[i];
  }
}

// ---------------- CSR build (global atomics; order within row is arbitrary,
// which only reassociates the per-row sum — within tolerance) ----------------

__global__ void zero_k(int* __restrict__ p, int n){
  int i = blockIdx.x*256 + threadIdx.x;
  if (i < n) p[i] = 0;
}

__global__ void hist_g(const int* __restrict__ rows, int* __restrict__ cnt, int E){
  int e = blockIdx.x*256 + threadIdx.x;
  if (e < E) atomicAdd(&cnt[rows[e]], 1);
}

// exclusive scan within 1024-element blocks; block total -> bsum
__global__ void scan_blk(const int* __restrict__ cnt, int* __restrict__ rp,
                         int* __restrict__ bsum, int V){
  __shared__ int sh[1024];
  int tid = threadIdx.x;
  int i = blockIdx.x*1024 + tid;
  int v = (i < V) ? cnt[i] : 0;
  sh[tid] = v;
  __syncthreads();
  for (int off = 1; off < 1024; off <<= 1){
    int t = (tid >= off) ? sh[tid - off] : 0;
    __syncthreads();
    sh[tid] += t;
    __syncthreads();
  }
  if (i < V) rp[i] = sh[tid] - v;            // exclusive within block
  if (tid == 1023) bsum[blockIdx.x] = sh[1023];
}

// exclusive scan of block sums (nb <= 48) — trivial serial
__global__ void scan_top(int* __restrict__ bsum, int nb){
  if (threadIdx.x == 0){
    int run = 0;
    for (int b = 0; b < nb; b++){ int t = bsum[b]; bsum[b] = run; run += t; }
  }
}

// add block offsets; produce rp (final row pointers) and rpw (mutable copy)
__global__ void scan_add(int* __restrict__ rp, int* __restrict__ rpw,
                         const int* __restrict__ bsum, int V, int E){
  int i = blockIdx.x*256 + threadIdx.x;
  if (i < V){
    int v = rp[i] + bsum[i >> 10];
    rp[i] = v;
    rpw[i] = v;
  }
  if (i == 0) rp[V] = E;
}

__global__ void scatter_g(const int* __restrict__ rows, const int* __restrict__ cols,
                          const float* __restrict__ vals,
                          int* __restrict__ rpw, int* __restrict__ cs,
                          float* __restrict__ vs, int E){
  int e = blockIdx.x*256 + threadIdx.x;
  if (e < E){
    int r = rows[e];
    int pos = atomicAdd(&rpw[r], 1);
    if (pos >= 0 && pos < E){
      cs[pos] = cols[e];
      vs[pos] = vals[e];
    }
  }
}

// ---------------- SpMV: float4 row-gather ----------------
__global__ __launch_bounds__(256) void spmv_gather4(
    const int* __restrict__ rp, const int* __restrict__ cs, const float* __restrict__ vs,
    const float4* __restrict__ xin, const float4* __restrict__ xprev,
    float4* __restrict__ xout, int V, int lf4, float alpha, float beta){
  long t = (long)blockIdx.x*256 + threadIdx.x;
  if (t >= ((long)V << lf4)) return;
  int r  = (int)(t >> lf4);
  int f4 = (int)(t - ((long)r << lf4));
  int j0 = rp[r], j1 = rp[r+1];
  float ax = 0.f, ay = 0.f, az = 0.f, aw = 0.f;
  for (int j = j0; j < j1; j++){
    int   c = cs[j];
    float v = vs[j];
    float4 g = xin[((long)c << lf4) + f4];
    ax = fmaf(v, g.x, ax); ay = fmaf(v, g.y, ay);
    az = fmaf(v, g.z, az); aw = fmaf(v, g.w, aw);
  }
  float4 o;
  o.x = alpha*ax; o.y = alpha*ay; o.z = alpha*az; o.w = alpha*aw;
  if (xprev){
    float4 p = xprev[t];
    o.x = fmaf(beta, p.x, o.x); o.y = fmaf(beta, p.y, o.y);
    o.z = fmaf(beta, p.z, o.z); o.w = fmaf(beta, p.w, o.w);
  }
  xout[t] = o;
}

// ---------------- multi-k tiled GEMM ----------------
// C[M,Co] (acc?+=:=) sum_{kk<nk} A_kk[M,Ci] @ W[kk][Ci,Co]
// W slices contiguous at W + kk*Ci*Co, staged in LDS one at a time.
// Register accumulation across all nk phases; C touched once.
template<int TN>
__global__ __launch_bounds__(256) void gemm_multi(
    const float* __restrict__ A0, const float* __restrict__ A1, const float* __restrict__ A2,
    const float* __restrict__ W, const float* __restrict__ bias, float* __restrict__ C,
    int Ci, int Co, int nk, int acc, int do_elu){
  extern __shared__ float ws[];   // Ci*Co floats
  int tid = threadIdx.x;
  int nw = Ci*Co;
  const int tc = tid & 15, tr = tid >> 4;
  const long r0 = (long)blockIdx.x * ROWS + (long)tr * 4;

  float accv[4][TN];
  #pragma unroll
  for (int m = 0; m < 4; m++)
    #pragma unroll
    for (int j = 0; j < TN; j++) accv[m][j] = 0.f;

  for (int kk = 0; kk < nk; kk++){
    const float* Ak = (kk == 0) ? A0 : ((kk == 1) ? A1 : A2);
    const float* Wk = W + (size_t)kk * nw;
    if (kk) __syncthreads();                 // previous phase done reading ws
    for (int i = tid; i < nw; i += 256) ws[i] = Wk[i];
    __syncthreads();

    const float* Ar = Ak + r0 * Ci;
    if ((Ci & 3) == 0){
      for (int i = 0; i < Ci; i += 4){
        float4 a0 = *(const float4*)(Ar + 0*Ci + i);
        float4 a1 = *(const float4*)(Ar + 1*Ci + i);
        float4 a2 = *(const float4*)(Ar + 2*Ci + i);
        float4 a3 = *(const float4*)(Ar + 3*Ci + i);
        float am[4][4] = {{a0.x,a0.y,a0.z,a0.w},{a1.x,a1.y,a1.z,a1.w},
                          {a2.x,a2.y,a2.z,a2.w},{a3.x,a3.y,a3.z,a3.w}};
        #pragma unroll
        for (int ii = 0; ii < 4; ii++){
          const float* wr = &ws[(i+ii)*Co + tc];
          #pragma unroll
          for (int j = 0; j < TN; j++){
            float wv = wr[j*16];
            #pragma unroll
            for (int m = 0; m < 4; m++)
              accv[m][j] = fmaf(am[m][ii], wv, accv[m][j]);
          }
        }
      }
    } else {
      for (int i = 0; i < Ci; i++){
        float am[4] = {Ar[0*Ci+i], Ar[1*Ci+i], Ar[2*Ci+i], Ar[3*Ci+i]};
        const float* wr = &ws[i*Co + tc];
        #pragma unroll
        for (int j = 0; j < TN; j++){
          float wv = wr[j*16];
          #pragma unroll
          for (int m = 0; m < 4; m++)
            accv[m][j] = fmaf(am[m], wv, accv[m][j]);
        }
      }
    }
  }

  #pragma unroll
  for (int m = 0; m < 4; m++){
    float* Cr = C + (r0 + m)*Co;
    #pragma unroll
    for (int j = 0; j < TN; j++){
      int col = tc + j*16;
      float v = accv[m][j];
      if (acc) v += Cr[col];
      if (do_elu) v = elu_f(v + bias[col]);
      Cr[col] = v;
    }
  }
}

static void launch_gemm_multi(const float* A0, const float* A1, const float* A2,
                              const float* W, const float* bias, float* C,
                              long M, int Ci, int Co, int nk, int acc, int do_elu,
                              hipStream_t stream){
  int grid = (int)(M / ROWS);
  size_t sh = (size_t)Ci * Co * sizeof(float);
  int tn = Co / 16;
  if (tn == 2)      gemm_multi<2><<<grid, 256, sh, stream>>>(A0, A1, A2, W, bias, C, Ci, Co, nk, acc, do_elu);
  else if (tn == 4) gemm_multi<4><<<grid, 256, sh, stream>>>(A0, A1, A2, W, bias, C, Ci, Co, nk, acc, do_elu);
  else              gemm_multi<8><<<grid, 256, sh, stream>>>(A0, A1, A2, W, bias, C, Ci, Co, nk, acc, do_elu);
}

// out2 [V,B,C] pre-bias -> skip (d_out, [B,V,C] fp32), pooled -> nx [V/4,B,C] fp32,
// optional pooled -> pool_out (d_out, [B,V/4,C] fp32)
__global__ void epilogue_k(const float* __restrict__ out2, const float* __restrict__ bias,
                           float* __restrict__ skip_out, float* __restrict__ nx,
                           float* __restrict__ pool_out, int V, int C){
  long t = (long)blockIdx.x*256 + threadIdx.x;
  long total = (long)(V/4)*BB*C;
  if (t >= total) return;
  int  c  = (int)(t % C);
  long bv = t / C;
  int  b  = (int)(bv % BB);
  int  v2 = (int)(bv / BB);
  float bia = bias[c];
  float s = 0.f;
  for (int j = 0; j < 4; j++){
    long v = (long)4*v2 + j;
    float val = elu_f(out2[(v*BB + b)*C + c] + bia);
    skip_out[((long)b*V + v)*C + c] = val;
    s += val;
  }
  s *= 0.25f;
  nx[((long)v2*BB + b)*C + c] = s;
  if (pool_out) pool_out[((long)b*(V/4) + v2)*C + c] = s;
}

__global__ void guard_k(float* __restrict__ out0, int code){
  if (threadIdx.x == 0) out0[0] = 1.0e6f + (float)code;
}

// ---------------- host driver ----------------

static int ilog2(int x){ int l = 0; while ((1 << l) < x) l++; return l; }

// One ChebConv: out = sum_k T_k(L) x0 @ w[k]; bias!=null fuses bias+ELU on last pass.
// k-groups of 3 share one GEMM launch (buffers hold x_{k-2},x_{k-1},x_k after each spmv).
static void run_cheb(float* x0, float* p1, float* p2, float* outb,
                     const float* w, const float* bias,
                     int V, int Ci, int Co, const int* rp, const int* cs, const float* vs,
                     hipStream_t stream){
  long M = (long)V*BB;
  int F4 = BB*Ci/4;
  int lf4 = ilog2(F4);
  long n4 = (long)V*F4;
  size_t wstep = (size_t)Ci*Co;

  // x1 = L x0 ; x2 = 2 L x1 - x0
  spmv_gather4<<<GRD(n4), 256, 0, stream>>>(rp, cs, vs, (const float4*)x0, nullptr,
                                            (float4*)p1, V, lf4, 1.f, 0.f);
  spmv_gather4<<<GRD(n4), 256, 0, stream>>>(rp, cs, vs, (const float4*)p1,
                                            (const float4*)x0, (float4*)p2, V, lf4,
                                            2.f, -1.f);
  launch_gemm_multi(x0, p1, p2, w, bias, outb, M, Ci, Co, 3, 0, 0, stream);

  float *b0 = x0, *b1 = p1, *b2 = p2;
  for (int k0 = 3; k0 + 2 < KCH; k0 += 3){
    // x_{k0}   = 2 L b2 - b1 -> b0
    spmv_gather4<<<GRD(n4), 256, 0, stream>>>(rp, cs, vs, (const float4*)b2,
                                              (const float4*)b1, (float4*)b0, V, lf4, 2.f, -1.f);
    // x_{k0+1} = 2 L b0 - b2 -> b1
    spmv_gather4<<<GRD(n4), 256, 0, stream>>>(rp, cs, vs, (const float4*)b0,
                                              (const float4*)b2, (float4*)b1, V, lf4, 2.f, -1.f);
    // x_{k0+2} = 2 L b1 - b0 -> b2
    spmv_gather4<<<GRD(n4), 256, 0, stream>>>(rp, cs, vs, (const float4*)b1,
                                              (const float4*)b0, (float4*)b2, V, lf4, 2.f, -1.f);
    launch_gemm_multi(b0, b1, b2, w + (size_t)k0*wstep, bias, outb, M, Ci, Co, 3, 1, 0, stream);
  }
  // final k = KCH-1 (KCH % 3 == 1): x9 = 2 L b2 - b1 -> b0
  spmv_gather4<<<GRD(n4), 256, 0, stream>>>(rp, cs, vs, (const float4*)b2,
                                            (const float4*)b1, (float4*)b0, V, lf4, 2.f, -1.f);
  launch_gemm_multi(b0, b0, b0, w + (size_t)(KCH-1)*wstep, bias, outb, M, Ci, Co, 1, 1,
                    bias ? 1 : 0, stream);
}

extern "C" void kernel_launch(void* const* d_in, const int* in_sizes, int n_in,
                              void* d_out, int out_size, void* d_ws, size_t ws_size,
                              hipStream_t stream){
  const float* x_in  = (const float*)d_in[0];
  const float* w1[3] = {(const float*)d_in[1], (const float*)d_in[8],  (const float*)d_in[15]};
  const float* b1[3] = {(const float*)d_in[2], (const float*)d_in[9],  (const float*)d_in[16]};
  const float* w2[3] = {(const float*)d_in[3], (const float*)d_in[10], (const float*)d_in[17]};
  const float* b2[3] = {(const float*)d_in[4], (const float*)d_in[11], (const float*)d_in[18]};
  const int*  rows[3]= {(const int*)d_in[5],   (const int*)d_in[12],   (const int*)d_in[19]};
  const int*  cols[3]= {(const int*)d_in[6],   (const int*)d_in[13],   (const int*)d_in[20]};
  const float* vals[3]={(const float*)d_in[7], (const float*)d_in[14], (const float*)d_in[21]};
  float* out = (float*)d_out;

  const int V[3] = {49152, 12288, 3072};
  const int E[3] = {393216, 98304, 24576};
  const int Ci1[3] = {1, 32, 64};
  const int Co1[3] = {32, 64, 128};

  // ---- workspace layout (fp32 units) ----
  float* wsf = (float*)d_ws;
  size_t off = 0;
  const size_t BUFSZ = (size_t)49152 * BB * 32;   // 12,582,912 floats
  float* BUF0 = wsf + off; off += BUFSZ;
  float* BUF1 = wsf + off; off += BUFSZ;
  float* BUF2 = wsf + off; off += BUFSZ;
  float* BUF3 = wsf + off; off += BUFSZ;
  float* NX   = wsf + off; off += (size_t)12288 * BB * 32;
  int* rp[3]; int* cs[3]; float* vsf[3];
  for (int i = 0; i < 3; i++){
    rp[i]  = (int*)(wsf + off); off += V[i] + 1;
    cs[i]  = (int*)(wsf + off); off += E[i];
    vsf[i] =        wsf + off;  off += E[i];
  }
  int* cntw = (int*)(wsf + off); off += 49152;
  int* bsum = (int*)(wsf + off); off += 64;
  int* rpw  = (int*)(wsf + off); off += 49152;
  if (ws_size < off * sizeof(float)) return;

  // ---- CSR build per level (fully parallel, global atomics) ----
  for (int i = 0; i < 3; i++){
    zero_k   <<<GRD(V[i]), 256, 0, stream>>>(cntw, V[i]);
    hist_g   <<<GRD(E[i]), 256, 0, stream>>>(rows[i], cntw, E[i]);
    int nb = (V[i] + 1023) / 1024;
    scan_blk <<<nb, 1024, 0, stream>>>(cntw, rp[i], bsum, V[i]);
    scan_top <<<1, 64, 0, stream>>>(bsum, nb);
    scan_add <<<GRD(V[i]), 256, 0, stream>>>(rp[i], rpw, bsum, V[i], E[i]);
    scatter_g<<<GRD(E[i]), 256, 0, stream>>>(rows[i], cols[i], vals[i],
                                             rpw, cs[i], vsf[i], E[i]);
  }

  // ---- level 0 input: [B,V] -> [V,B,1] ----
  transpose_in<<<GRD(BB*V[0]), 256, 0, stream>>>(x_in, NX, V[0]);

  const long OFF_OUT[4] = {0, 12582912, 18874368, 22020096};

  for (int lvl = 0; lvl < 3; lvl++){
    int Vv = V[lvl];
    int Cm = Co1[lvl];
    // conv1: NX -> BUF0 (bias+ELU fused into final GEMM pass)
    run_cheb(NX, BUF1, BUF2, BUF0, w1[lvl], b1[lvl], Vv, Ci1[lvl], Cm,
             rp[lvl], cs[lvl], vsf[lvl], stream);
    // conv2: BUF0 -> BUF3 (raw; epilogue applies bias+ELU+pool)
    run_cheb(BUF0, BUF1, BUF2, BUF3, w2[lvl], nullptr, Vv, Cm, Cm,
             rp[lvl], cs[lvl], vsf[lvl], stream);
    long n2 = (long)(Vv/4) * BB * Cm;
    float* pool_out = (lvl == 2) ? (out + OFF_OUT[3]) : (float*)nullptr;
    epilogue_k<<<GRD(n2), 256, 0, stream>>>(BUF3, b2[lvl],
                                            out + OFF_OUT[lvl], NX, pool_out,
                                            Vv, Cm);
  }

  if (out_size != 22806528)
    guard_k<<<1, 64, 0, stream>>>(out, out_size % 4096);
}

// Round 2
// 2849.519 us; speedup vs baseline: 1.2093x; 1.0227x over previous
//
#include <hip/hip_runtime.h>
#include <math.h>

#define BB 8      // batch
#define KCH 10    // Chebyshev order
#define ROWS 64   // GEMM rows per block
#define GRD(n) ((int)(((n) + 255) / 256))

__device__ __forceinline__ float elu_f(float x){ return x > 0.f ? x : expf(x) - 1.f; }

// x input is [B, V] fp32 -> x0 [V, B] fp32
__global__ void transpose_in(const float* __restrict__ x, float* __restrict__ x0, int V){
  int i = blockIdx.x*256 + threadIdx.x;
  if (i < BB*V){
    int b = i / V, v = i - b*V;
    x0[(long)v*BB + b] = x[i];
  }
}

// ---------------- CSR build (global atomics; order within row is arbitrary,
// which only reassociates the per-row sum — within tolerance) ----------------

__global__ void zero_k(int* __restrict__ p, int n){
  int i = blockIdx.x*256 + threadIdx.x;
  if (i < n) p[i] = 0;
}

__global__ void hist_g(const int* __restrict__ rows, int* __restrict__ cnt, int E){
  int e = blockIdx.x*256 + threadIdx.x;
  if (e < E) atomicAdd(&cnt[rows[e]], 1);
}

// exclusive scan within 1024-element blocks; block total -> bsum
__global__ void scan_blk(const int* __restrict__ cnt, int* __restrict__ rp,
                         int* __restrict__ bsum, int V){
  __shared__ int sh[1024];
  int tid = threadIdx.x;
  int i = blockIdx.x*1024 + tid;
  int v = (i < V) ? cnt[i] : 0;
  sh[tid] = v;
  __syncthreads();
  for (int off = 1; off < 1024; off <<= 1){
    int t = (tid >= off) ? sh[tid - off] : 0;
    __syncthreads();
    sh[tid] += t;
    __syncthreads();
  }
  if (i < V) rp[i] = sh[tid] - v;            // exclusive within block
  if (tid == 1023) bsum[blockIdx.x] = sh[1023];
}

// exclusive scan of block sums (nb <= 48) — trivial serial
__global__ void scan_top(int* __restrict__ bsum, int nb){
  if (threadIdx.x == 0){
    int run = 0;
    for (int b = 0; b < nb; b++){ int t = bsum[b]; bsum[b] = run; run += t; }
  }
}

// add block offsets; produce rp (final row pointers) and rpw (mutable copy)
__global__ void scan_add(int* __restrict__ rp, int* __restrict__ rpw,
                         const int* __restrict__ bsum, int V, int E){
  int i = blockIdx.x*256 + threadIdx.x;
  if (i < V){
    int v = rp[i] + bsum[i >> 10];
    rp[i] = v;
    rpw[i] = v;
  }
  if (i == 0) rp[V] = E;
}

__global__ void scatter_g(const int* __restrict__ rows, const int* __restrict__ cols,
                          const float* __restrict__ vals,
                          int* __restrict__ rpw, int* __restrict__ cs,
                          float* __restrict__ vs, int E){
  int e = blockIdx.x*256 + threadIdx.x;
  if (e < E){
    int r = rows[e];
    int pos = atomicAdd(&rpw[r], 1);
    if (pos >= 0 && pos < E){
      cs[pos] = cols[e];
      vs[pos] = vals[e];
    }
  }
}

// ---------------- SpMV: float4 row-gather ----------------
__global__ __launch_bounds__(256) void spmv_gather4(
    const int* __restrict__ rp, const int* __restrict__ cs, const float* __restrict__ vs,
    const float4* __restrict__ xin, const float4* __restrict__ xprev,
    float4* __restrict__ xout, int V, int lf4, float alpha, float beta){
  long t = (long)blockIdx.x*256 + threadIdx.x;
  if (t >= ((long)V << lf4)) return;
  int r  = (int)(t >> lf4);
  int f4 = (int)(t - ((long)r << lf4));
  int j0 = rp[r], j1 = rp[r+1];
  float ax = 0.f, ay = 0.f, az = 0.f, aw = 0.f;
  for (int j = j0; j < j1; j++){
    int   c = cs[j];
    float v = vs[j];
    float4 g = xin[((long)c << lf4) + f4];
    ax = fmaf(v, g.x, ax); ay = fmaf(v, g.y, ay);
    az = fmaf(v, g.z, az); aw = fmaf(v, g.w, aw);
  }
  float4 o;
  o.x = alpha*ax; o.y = alpha*ay; o.z = alpha*az; o.w = alpha*aw;
  if (xprev){
    float4 p = xprev[t];
    o.x = fmaf(beta, p.x, o.x); o.y = fmaf(beta, p.y, o.y);
    o.z = fmaf(beta, p.z, o.z); o.w = fmaf(beta, p.w, o.w);
  }
  xout[t] = o;
}

// ---------------- multi-k tiled GEMM, compile-time dims ----------------
// C[M,CO] (acc?+=:=) sum_{kk<NK} A_kk[M,CI] @ W[kk][CI,CO]
// All NK W slices staged in LDS upfront when <=64KB (one sync per block);
// else per-phase staging. Register accumulation; C touched once.

template<int CI, int CO, int TN>
__device__ __forceinline__ void gstep4(const float* __restrict__ Ar,
                                       const float* __restrict__ wsl,
                                       int i, int tc, float (&accv)[4][TN]){
  float4 a0 = *(const float4*)(Ar + 0*CI + i);
  float4 a1 = *(const float4*)(Ar + 1*CI + i);
  float4 a2 = *(const float4*)(Ar + 2*CI + i);
  float4 a3 = *(const float4*)(Ar + 3*CI + i);
  float am[4][4] = {{a0.x,a0.y,a0.z,a0.w},{a1.x,a1.y,a1.z,a1.w},
                    {a2.x,a2.y,a2.z,a2.w},{a3.x,a3.y,a3.z,a3.w}};
  #pragma unroll
  for (int ii = 0; ii < 4; ii++){
    const float* wr = &wsl[(i+ii)*CO + tc];
    #pragma unroll
    for (int j = 0; j < TN; j++){
      float wv = wr[j*16];
      #pragma unroll
      for (int m = 0; m < 4; m++)
        accv[m][j] = fmaf(am[m][ii], wv, accv[m][j]);
    }
  }
}

template<int CI, int CO, int NK>
__global__ __launch_bounds__(256) void gemm_multi(
    const float* __restrict__ A0, const float* __restrict__ A1,
    const float* __restrict__ A2, const float* __restrict__ A3,
    const float* __restrict__ W, const float* __restrict__ bias,
    float* __restrict__ C, int acc, int do_elu){
  constexpr int TN = CO/16;
  constexpr int NW = CI*CO;
  constexpr bool UP = ((size_t)NK*NW*4 <= 65536);
  __shared__ float ws[UP ? NK*NW : NW];

  const int tid = threadIdx.x;
  const int tc = tid & 15, tr = tid >> 4;
  const long r0 = (long)blockIdx.x * ROWS + (long)tr * 4;

  if constexpr (UP){
    const float4* W4 = (const float4*)W;
    for (int i = tid; i < NK*NW/4; i += 256) ((float4*)ws)[i] = W4[i];
    __syncthreads();
  }

  float accv[4][TN];
  #pragma unroll
  for (int m = 0; m < 4; m++)
    #pragma unroll
    for (int j = 0; j < TN; j++) accv[m][j] = 0.f;

  #pragma unroll 1
  for (int kk = 0; kk < NK; kk++){
    const float* Ak = (kk == 0) ? A0 : ((kk == 1) ? A1 : ((kk == 2) ? A2 : A3));
    const float* wsl;
    if constexpr (UP){
      wsl = ws + kk*NW;
    } else {
      if (kk) __syncthreads();
      const float4* Wk4 = (const float4*)(W + (size_t)kk*NW);
      for (int i = tid; i < NW/4; i += 256) ((float4*)ws)[i] = Wk4[i];
      __syncthreads();
      wsl = ws;
    }
    const float* Ar = Ak + r0*CI;
    if constexpr (CI == 1){
      float4 a = *(const float4*)Ar;   // 4 consecutive rows, Ci=1
      float am[4] = {a.x, a.y, a.z, a.w};
      const float* wr = &wsl[tc];
      #pragma unroll
      for (int j = 0; j < TN; j++){
        float wv = wr[j*16];
        #pragma unroll
        for (int m = 0; m < 4; m++)
          accv[m][j] = fmaf(am[m], wv, accv[m][j]);
      }
    } else if constexpr (CI*CO <= 2048){
      #pragma unroll
      for (int i = 0; i < CI; i += 4) gstep4<CI,CO,TN>(Ar, wsl, i, tc, accv);
    } else if constexpr (CI >= 128){
      #pragma unroll 4
      for (int i = 0; i < CI; i += 4) gstep4<CI,CO,TN>(Ar, wsl, i, tc, accv);
    } else {
      #pragma unroll 8
      for (int i = 0; i < CI; i += 4) gstep4<CI,CO,TN>(Ar, wsl, i, tc, accv);
    }
  }

  #pragma unroll
  for (int m = 0; m < 4; m++){
    float* Cr = C + (r0 + m)*CO;
    #pragma unroll
    for (int j = 0; j < TN; j++){
      int col = tc + j*16;
      float v = accv[m][j];
      if (acc) v += Cr[col];
      if (do_elu) v = elu_f(v + bias[col]);
      Cr[col] = v;
    }
  }
}

static void launch_gemm(const float* A0, const float* A1, const float* A2, const float* A3,
                        const float* W, const float* bias, float* C,
                        long M, int Ci, int Co, int nk, int acc, int do_elu,
                        hipStream_t st){
  int grid = (int)(M / ROWS);
#define GCASE(ci,co) \
  if (Ci == ci && Co == co){ \
    if (nk == 4) gemm_multi<ci,co,4><<<grid,256,0,st>>>(A0,A1,A2,A3,W,bias,C,acc,do_elu); \
    else         gemm_multi<ci,co,3><<<grid,256,0,st>>>(A0,A1,A2,A3,W,bias,C,acc,do_elu); \
    return; }
  GCASE(1,32) GCASE(32,32) GCASE(32,64) GCASE(64,64) GCASE(64,128) GCASE(128,128)
#undef GCASE
}

// out2 [V,B,C] pre-bias -> skip (d_out, [B,V,C] fp32), pooled -> nx [V/4,B,C] fp32,
// optional pooled -> pool_out (d_out, [B,V/4,C] fp32)
__global__ void epilogue_k(const float* __restrict__ out2, const float* __restrict__ bias,
                           float* __restrict__ skip_out, float* __restrict__ nx,
                           float* __restrict__ pool_out, int V, int C){
  long t = (long)blockIdx.x*256 + threadIdx.x;
  long total = (long)(V/4)*BB*C;
  if (t >= total) return;
  int  c  = (int)(t % C);
  long bv = t / C;
  int  b  = (int)(bv % BB);
  int  v2 = (int)(bv / BB);
  float bia = bias[c];
  float s = 0.f;
  for (int j = 0; j < 4; j++){
    long v = (long)4*v2 + j;
    float val = elu_f(out2[(v*BB + b)*C + c] + bia);
    skip_out[((long)b*V + v)*C + c] = val;
    s += val;
  }
  s *= 0.25f;
  nx[((long)v2*BB + b)*C + c] = s;
  if (pool_out) pool_out[((long)b*(V/4) + v2)*C + c] = s;
}

__global__ void guard_k(float* __restrict__ out0, int code){
  if (threadIdx.x == 0) out0[0] = 1.0e6f + (float)code;
}

// ---------------- host driver ----------------

static int ilog2(int x){ int l = 0; while ((1 << l) < x) l++; return l; }

// One ChebConv with 4-buffer rotation: x_k -> q[k&3]. k-groups {0-3},{4-6},{7-9}.
// bias!=null fuses bias+ELU on the last group's epilogue.
static void run_cheb(float* q0, float* q1, float* q2, float* q3, float* outb,
                     const float* w, const float* bias,
                     int V, int Ci, int Co, const int* rp, const int* cs, const float* vs,
                     hipStream_t stream){
  long M = (long)V*BB;
  int F4 = BB*Ci/4;
  int lf4 = ilog2(F4);
  long n4 = (long)V*F4;
  size_t wstep = (size_t)Ci*Co;
  float* q[4] = {q0, q1, q2, q3};

  // x1 = L x0 ; x2 = 2 L x1 - x0 ; x3 = 2 L x2 - x1
  spmv_gather4<<<GRD(n4), 256, 0, stream>>>(rp, cs, vs, (const float4*)q0, nullptr,
                                            (float4*)q1, V, lf4, 1.f, 0.f);
  spmv_gather4<<<GRD(n4), 256, 0, stream>>>(rp, cs, vs, (const float4*)q1,
                                            (const float4*)q0, (float4*)q2, V, lf4, 2.f, -1.f);
  spmv_gather4<<<GRD(n4), 256, 0, stream>>>(rp, cs, vs, (const float4*)q2,
                                            (const float4*)q1, (float4*)q3, V, lf4, 2.f, -1.f);
  launch_gemm(q0, q1, q2, q3, w, bias, outb, M, Ci, Co, 4, 0, 0, stream);

  for (int k0 = 4; k0 < KCH; k0 += 3){
    int kn = (KCH - k0 < 3) ? (KCH - k0) : 3;   // 3,3 for KCH=10
    for (int k = k0; k < k0 + kn; k++){
      float* dst = q[k & 3];
      float* src = q[(k-1) & 3];
      float* prv = q[(k-2) & 3];
      spmv_gather4<<<GRD(n4), 256, 0, stream>>>(rp, cs, vs, (const float4*)src,
                                                (const float4*)prv, (float4*)dst, V, lf4,
                                                2.f, -1.f);
    }
    int last = (k0 + kn == KCH) ? 1 : 0;
    launch_gemm(q[k0 & 3], q[(k0+1) & 3], q[(k0+2) & 3], nullptr,
                w + (size_t)k0*wstep, bias, outb, M, Ci, Co, kn, 1,
                (bias && last) ? 1 : 0, stream);
  }
}

extern "C" void kernel_launch(void* const* d_in, const int* in_sizes, int n_in,
                              void* d_out, int out_size, void* d_ws, size_t ws_size,
                              hipStream_t stream){
  const float* x_in  = (const float*)d_in[0];
  const float* w1[3] = {(const float*)d_in[1], (const float*)d_in[8],  (const float*)d_in[15]};
  const float* b1[3] = {(const float*)d_in[2], (const float*)d_in[9],  (const float*)d_in[16]};
  const float* w2[3] = {(const float*)d_in[3], (const float*)d_in[10], (const float*)d_in[17]};
  const float* b2[3] = {(const float*)d_in[4], (const float*)d_in[11], (const float*)d_in[18]};
  const int*  rows[3]= {(const int*)d_in[5],   (const int*)d_in[12],   (const int*)d_in[19]};
  const int*  cols[3]= {(const int*)d_in[6],   (const int*)d_in[13],   (const int*)d_in[20]};
  const float* vals[3]={(const float*)d_in[7], (const float*)d_in[14], (const float*)d_in[21]};
  float* out = (float*)d_out;

  const int V[3] = {49152, 12288, 3072};
  const int E[3] = {393216, 98304, 24576};
  const int Ci1[3] = {1, 32, 64};
  const int Co1[3] = {32, 64, 128};

  // ---- workspace layout (fp32 units) ----
  float* wsf = (float*)d_ws;
  size_t off = 0;
  const size_t BUFSZ = (size_t)49152 * BB * 32;   // 12,582,912 floats
  float* BUF0 = wsf + off; off += BUFSZ;
  float* BUF1 = wsf + off; off += BUFSZ;
  float* BUF2 = wsf + off; off += BUFSZ;
  float* BUF3 = wsf + off; off += BUFSZ;
  float* NX   = wsf + off; off += (size_t)12288 * BB * 32;
  int* rp[3]; int* cs[3]; float* vsf[3];
  for (int i = 0; i < 3; i++){
    rp[i]  = (int*)(wsf + off); off += V[i] + 1;
    cs[i]  = (int*)(wsf + off); off += E[i];
    vsf[i] =        wsf + off;  off += E[i];
  }
  int* cntw = (int*)(wsf + off); off += 49152;
  int* bsum = (int*)(wsf + off); off += 64;
  int* rpw  = (int*)(wsf + off); off += 49152;
  if (ws_size < off * sizeof(float)) return;

  // ---- CSR build per level (fully parallel, global atomics) ----
  for (int i = 0; i < 3; i++){
    zero_k   <<<GRD(V[i]), 256, 0, stream>>>(cntw, V[i]);
    hist_g   <<<GRD(E[i]), 256, 0, stream>>>(rows[i], cntw, E[i]);
    int nb = (V[i] + 1023) / 1024;
    scan_blk <<<nb, 1024, 0, stream>>>(cntw, rp[i], bsum, V[i]);
    scan_top <<<1, 64, 0, stream>>>(bsum, nb);
    scan_add <<<GRD(V[i]), 256, 0, stream>>>(rp[i], rpw, bsum, V[i], E[i]);
    scatter_g<<<GRD(E[i]), 256, 0, stream>>>(rows[i], cols[i], vals[i],
                                             rpw, cs[i], vsf[i], E[i]);
  }

  // ---- level 0 input: [B,V] -> [V,B,1] ----
  transpose_in<<<GRD(BB*V[0]), 256, 0, stream>>>(x_in, NX, V[0]);

  const long OFF_OUT[4] = {0, 12582912, 18874368, 22020096};

  for (int lvl = 0; lvl < 3; lvl++){
    int Vv = V[lvl];
    int Cm = Co1[lvl];
    // conv1: NX -> BUF0. Rotation buffers BUF1,BUF2,BUF3 (BUF3 free here).
    run_cheb(NX, BUF1, BUF2, BUF3, BUF0, w1[lvl], b1[lvl], Vv, Ci1[lvl], Cm,
             rp[lvl], cs[lvl], vsf[lvl], stream);
    // conv2: BUF0 -> BUF3. 4th rotation buffer = this level's skip region of d_out
    // (sized exactly V*BB*Cm; fully overwritten by epilogue afterwards).
    float* skipreg = out + OFF_OUT[lvl];
    run_cheb(BUF0, BUF1, BUF2, skipreg, BUF3, w2[lvl], nullptr, Vv, Cm, Cm,
             rp[lvl], cs[lvl], vsf[lvl], stream);
    long n2 = (long)(Vv/4) * BB * Cm;
    float* pool_out = (lvl == 2) ? (out + OFF_OUT[3]) : (float*)nullptr;
    epilogue_k<<<GRD(n2), 256, 0, stream>>>(BUF3, b2[lvl],
                                            out + OFF_OUT[lvl], NX, pool_out,
                                            Vv, Cm);
  }

  if (out_size != 22806528)
    guard_k<<<1, 64, 0, stream>>>(out, out_size % 4096);
}

// Round 3
// 2564.525 us; speedup vs baseline: 1.3437x; 1.1111x over previous
//
#include <hip/hip_runtime.h>
#include <math.h>

#define BB 8      // batch
#define KCH 10    // Chebyshev order
#define GRD(n) ((int)(((n) + 255) / 256))

__device__ __forceinline__ float elu_f(float x){ return x > 0.f ? x : expf(x) - 1.f; }

// x input is [B, V] fp32 -> x0 [V, B] fp32
__global__ void transpose_in(const float* __restrict__ x, float* __restrict__ x0, int V){
  int i = blockIdx.x*256 + threadIdx.x;
  if (i < BB*V){
    int b = i / V, v = i - b*V;
    x0[(long)v*BB + b] = x[i];
  }
}

// ---------------- CSR build (global atomics; order within row is arbitrary,
// which only reassociates the per-row sum — within tolerance) ----------------

__global__ void zero_k(int* __restrict__ p, int n){
  int i = blockIdx.x*256 + threadIdx.x;
  if (i < n) p[i] = 0;
}

__global__ void hist_g(const int* __restrict__ rows, int* __restrict__ cnt, int E){
  int e = blockIdx.x*256 + threadIdx.x;
  if (e < E) atomicAdd(&cnt[rows[e]], 1);
}

// exclusive scan within 1024-element blocks; block total -> bsum
__global__ void scan_blk(const int* __restrict__ cnt, int* __restrict__ rp,
                         int* __restrict__ bsum, int V){
  __shared__ int sh[1024];
  int tid = threadIdx.x;
  int i = blockIdx.x*1024 + tid;
  int v = (i < V) ? cnt[i] : 0;
  sh[tid] = v;
  __syncthreads();
  for (int off = 1; off < 1024; off <<= 1){
    int t = (tid >= off) ? sh[tid - off] : 0;
    __syncthreads();
    sh[tid] += t;
    __syncthreads();
  }
  if (i < V) rp[i] = sh[tid] - v;            // exclusive within block
  if (tid == 1023) bsum[blockIdx.x] = sh[1023];
}

// exclusive scan of block sums (nb <= 48) — trivial serial
__global__ void scan_top(int* __restrict__ bsum, int nb){
  if (threadIdx.x == 0){
    int run = 0;
    for (int b = 0; b < nb; b++){ int t = bsum[b]; bsum[b] = run; run += t; }
  }
}

// add block offsets; produce rp (final row pointers) and rpw (mutable copy)
__global__ void scan_add(int* __restrict__ rp, int* __restrict__ rpw,
                         const int* __restrict__ bsum, int V, int E){
  int i = blockIdx.x*256 + threadIdx.x;
  if (i < V){
    int v = rp[i] + bsum[i >> 10];
    rp[i] = v;
    rpw[i] = v;
  }
  if (i == 0) rp[V] = E;
}

__global__ void scatter_g(const int* __restrict__ rows, const int* __restrict__ cols,
                          const float* __restrict__ vals,
                          int* __restrict__ rpw, int* __restrict__ cs,
                          float* __restrict__ vs, int E){
  int e = blockIdx.x*256 + threadIdx.x;
  if (e < E){
    int r = rows[e];
    int pos = atomicAdd(&rpw[r], 1);
    if (pos >= 0 && pos < E){
      cs[pos] = cols[e];
      vs[pos] = vals[e];
    }
  }
}

// ---------------- SpMV: float4 row-gather ----------------
__global__ __launch_bounds__(256) void spmv_gather4(
    const int* __restrict__ rp, const int* __restrict__ cs, const float* __restrict__ vs,
    const float4* __restrict__ xin, const float4* __restrict__ xprev,
    float4* __restrict__ xout, int V, int lf4, float alpha, float beta){
  long t = (long)blockIdx.x*256 + threadIdx.x;
  if (t >= ((long)V << lf4)) return;
  int r  = (int)(t >> lf4);
  int f4 = (int)(t - ((long)r << lf4));
  int j0 = rp[r], j1 = rp[r+1];
  float ax = 0.f, ay = 0.f, az = 0.f, aw = 0.f;
  for (int j = j0; j < j1; j++){
    int   c = cs[j];
    float v = vs[j];
    float4 g = xin[((long)c << lf4) + f4];
    ax = fmaf(v, g.x, ax); ay = fmaf(v, g.y, ay);
    az = fmaf(v, g.z, az); aw = fmaf(v, g.w, aw);
  }
  float4 o;
  o.x = alpha*ax; o.y = alpha*ay; o.z = alpha*az; o.w = alpha*aw;
  if (xprev){
    float4 p = xprev[t];
    o.x = fmaf(beta, p.x, o.x); o.y = fmaf(beta, p.y, o.y);
    o.z = fmaf(beta, p.z, o.z); o.w = fmaf(beta, p.w, o.w);
  }
  xout[t] = o;
}

// ---------------- multi-k tiled GEMM, compile-time dims ----------------
// C[M,CO] (acc?+=:=) sum_{kk<nk} A_{k0+kk}[M,CI] @ W[k0+kk][CI,CO]
// A_k = (k==0) ? X0 : AR + ((k-1)%nfit)*slice   (arena of basis slices)
// In-place allowed for conv2: C == X0 (each thread reads only its own rows of
// A_0 before its final C write; rows are disjoint across threads/blocks).
// RT rows per thread; 16 col-threads; block covers 16*RT rows.

template<int CI, int CO, int TN, int RT>
__device__ __forceinline__ void gstep(const float* Ar, const float* __restrict__ wsl,
                                      int i, int tc, float (&accv)[RT][TN]){
  float am[RT][4];
  #pragma unroll
  for (int m = 0; m < RT; m++){
    float4 a = *(const float4*)(Ar + m*CI + i);
    am[m][0] = a.x; am[m][1] = a.y; am[m][2] = a.z; am[m][3] = a.w;
  }
  #pragma unroll
  for (int ii = 0; ii < 4; ii++){
    const float* wr = &wsl[(i+ii)*CO + tc];
    #pragma unroll
    for (int j = 0; j < TN; j++){
      float wv = wr[j*16];
      #pragma unroll
      for (int m = 0; m < RT; m++)
        accv[m][j] = fmaf(am[m][ii], wv, accv[m][j]);
    }
  }
}

template<int CI, int CO, int RT>
__global__ __launch_bounds__(256) void gemm_multi(
    const float* X0, const float* __restrict__ AR,
    const float* __restrict__ W, const float* __restrict__ bias,
    float* C, int k0, int nk, int nfit, long slice, int acc, int do_elu){
  constexpr int TN = CO/16;
  constexpr int NW = CI*CO;
  constexpr bool UP = (NW*40 <= 65536);   // all 10 W slices fit in 64KB LDS
  extern __shared__ float ws[];

  const int tid = threadIdx.x;
  const int tc = tid & 15, tr = tid >> 4;
  const long r0 = (long)blockIdx.x*(16*RT) + (long)tr*RT;

  if constexpr (UP){
    const float4* W4 = (const float4*)(W + (size_t)k0*NW);
    for (int i = tid; i < nk*NW/4; i += 256) ((float4*)ws)[i] = W4[i];
    __syncthreads();
  }

  float accv[RT][TN];
  #pragma unroll
  for (int m = 0; m < RT; m++)
    #pragma unroll
    for (int j = 0; j < TN; j++) accv[m][j] = 0.f;

  #pragma unroll 1
  for (int kk = 0; kk < nk; kk++){
    int k = k0 + kk;
    const float* Ak = (k == 0) ? X0 : AR + (size_t)((k-1) % nfit)*slice;
    const float* wsl;
    if constexpr (UP){
      wsl = ws + (size_t)kk*NW;
    } else {
      if (kk) __syncthreads();
      const float4* Wk4 = (const float4*)(W + (size_t)k*NW);
      for (int i = tid; i < NW/4; i += 256) ((float4*)ws)[i] = Wk4[i];
      __syncthreads();
      wsl = ws;
    }
    const float* Ar = Ak + r0*CI;
    if constexpr (CI == 1){
      float am[RT];
      #pragma unroll
      for (int m = 0; m < RT; m += 4){
        float4 a = *(const float4*)(Ar + m);
        am[m] = a.x; am[m+1] = a.y; am[m+2] = a.z; am[m+3] = a.w;
      }
      const float* wr = &wsl[tc];
      #pragma unroll
      for (int j = 0; j < TN; j++){
        float wv = wr[j*16];
        #pragma unroll
        for (int m = 0; m < RT; m++)
          accv[m][j] = fmaf(am[m], wv, accv[m][j]);
      }
    } else if constexpr (CI <= 32){
      #pragma unroll
      for (int i = 0; i < CI; i += 4) gstep<CI,CO,TN,RT>(Ar, wsl, i, tc, accv);
    } else {
      #pragma unroll 4
      for (int i = 0; i < CI; i += 4) gstep<CI,CO,TN,RT>(Ar, wsl, i, tc, accv);
    }
  }

  #pragma unroll
  for (int m = 0; m < RT; m++){
    float* Cr = C + (r0 + m)*CO;
    #pragma unroll
    for (int j = 0; j < TN; j++){
      int col = tc + j*16;
      float v = accv[m][j];
      if (acc) v += Cr[col];
      if (do_elu) v = elu_f(v + bias[col]);
      Cr[col] = v;
    }
  }
}

static void launch_gemm(const float* X0, const float* AR, const float* W, const float* bias,
                        float* C, long M, int Ci, int Co, int k0, int nk, int nfit,
                        long slice, int acc, int do_elu, hipStream_t st){
#define GC(ci,co,rt) \
  if (Ci == ci && Co == co){ \
    size_t sh = (size_t)((ci*co*40 <= 65536) ? nk*ci*co : ci*co) * 4; \
    gemm_multi<ci,co,rt><<<(int)(M/(16*rt)), 256, sh, st>>>( \
        X0, AR, W, bias, C, k0, nk, nfit, slice, acc, do_elu); \
    return; }
  GC(1,32,8) GC(32,32,8) GC(32,64,8) GC(64,64,8) GC(64,128,4) GC(128,128,4)
#undef GC
}

// out2 [V,B,C] pre-bias -> skip (d_out, [B,V,C] fp32), pooled -> nx [V/4,B,C] fp32,
// optional pooled -> pool_out (d_out, [B,V/4,C] fp32)
__global__ void epilogue_k(const float* __restrict__ out2, const float* __restrict__ bias,
                           float* __restrict__ skip_out, float* __restrict__ nx,
                           float* __restrict__ pool_out, int V, int C){
  long t = (long)blockIdx.x*256 + threadIdx.x;
  long total = (long)(V/4)*BB*C;
  if (t >= total) return;
  int  c  = (int)(t % C);
  long bv = t / C;
  int  b  = (int)(bv % BB);
  int  v2 = (int)(bv / BB);
  float bia = bias[c];
  float s = 0.f;
  for (int j = 0; j < 4; j++){
    long v = (long)4*v2 + j;
    float val = elu_f(out2[(v*BB + b)*C + c] + bia);
    skip_out[((long)b*V + v)*C + c] = val;
    s += val;
  }
  s *= 0.25f;
  nx[((long)v2*BB + b)*C + c] = s;
  if (pool_out) pool_out[((long)b*(V/4) + v2)*C + c] = s;
}

__global__ void guard_k(float* __restrict__ out0, int code){
  if (threadIdx.x == 0) out0[0] = 1.0e6f + (float)code;
}

// ---------------- host driver ----------------

static int ilog2(int x){ int l = 0; while ((1 << l) < x) l++; return l; }

// One ChebConv: out = sum_k T_k(L) x0 @ w[k].
// Basis slices x_1..x_9 live in a contiguous arena (nfit slices, modulo-indexed).
// GEMM groups: first min(10, nfit+1) terms, then chunks of nfit; C touched once
// per group. bias!=null fuses bias+ELU on the last group.
static void run_cheb(const float* x0, float* arena, long slice, int nfit,
                     float* outC, const float* w, const float* bias,
                     int V, int Ci, int Co, const int* rp, const int* cs, const float* vs,
                     hipStream_t stream){
  long M = (long)V*BB;
  int F4 = BB*Ci/4;
  int lf4 = ilog2(F4);
  long n4 = (long)V*F4;

  int k0 = 0;
  int g = (KCH < nfit + 1) ? KCH : nfit + 1;
  int next_k = 1;
  while (k0 < KCH){
    int kend = k0 + g;
    for (int k = next_k; k < kend; k++){
      float* dst = arena + (size_t)((k-1) % nfit)*slice;
      const float* src = (k >= 2) ? arena + (size_t)((k-2) % nfit)*slice : x0;
      const float* prv = (k >= 3) ? arena + (size_t)((k-3) % nfit)*slice
                                  : ((k == 2) ? x0 : nullptr);
      spmv_gather4<<<GRD(n4), 256, 0, stream>>>(rp, cs, vs, (const float4*)src,
                                                (const float4*)prv, (float4*)dst, V, lf4,
                                                (k == 1) ? 1.f : 2.f, (k == 1) ? 0.f : -1.f);
    }
    next_k = kend;
    launch_gemm(x0, arena, w, bias, outC, M, Ci, Co, k0, g, nfit, slice,
                (k0 > 0) ? 1 : 0, (bias && kend == KCH) ? 1 : 0, stream);
    k0 = kend;
    g = (KCH - k0 < nfit) ? (KCH - k0) : nfit;
  }
}

extern "C" void kernel_launch(void* const* d_in, const int* in_sizes, int n_in,
                              void* d_out, int out_size, void* d_ws, size_t ws_size,
                              hipStream_t stream){
  const float* x_in  = (const float*)d_in[0];
  const float* w1[3] = {(const float*)d_in[1], (const float*)d_in[8],  (const float*)d_in[15]};
  const float* b1[3] = {(const float*)d_in[2], (const float*)d_in[9],  (const float*)d_in[16]};
  const float* w2[3] = {(const float*)d_in[3], (const float*)d_in[10], (const float*)d_in[17]};
  const float* b2[3] = {(const float*)d_in[4], (const float*)d_in[11], (const float*)d_in[18]};
  const int*  rows[3]= {(const int*)d_in[5],   (const int*)d_in[12],   (const int*)d_in[19]};
  const int*  cols[3]= {(const int*)d_in[6],   (const int*)d_in[13],   (const int*)d_in[20]};
  const float* vals[3]={(const float*)d_in[7], (const float*)d_in[14], (const float*)d_in[21]};
  float* out = (float*)d_out;

  const int V[3] = {49152, 12288, 3072};
  const int E[3] = {393216, 98304, 24576};
  const int Ci1[3] = {1, 32, 64};
  const int Co1[3] = {32, 64, 128};

  // ---- workspace layout (fp32 units) ----
  float* wsf = (float*)d_ws;
  size_t off = 0;
  const size_t BUFSZ = (size_t)49152 * BB * 32;   // 12,582,912 floats
  float* BUF0 = wsf + off; off += BUFSZ;
  float* ARENA = wsf + off; off += 3*BUFSZ;       // BUF1..BUF3 contiguous
  float* NX   = wsf + off; off += (size_t)12288 * BB * 32;
  int* rp[3]; int* cs[3]; float* vsf[3];
  for (int i = 0; i < 3; i++){
    rp[i]  = (int*)(wsf + off); off += V[i] + 1;
    cs[i]  = (int*)(wsf + off); off += E[i];
    vsf[i] =        wsf + off;  off += E[i];
  }
  int* cntw = (int*)(wsf + off); off += 49152;
  int* bsum = (int*)(wsf + off); off += 64;
  int* rpw  = (int*)(wsf + off); off += 49152;
  if (ws_size < off * sizeof(float)) return;

  const long ARENA_F = (long)3*BUFSZ;

  // ---- CSR build per level (fully parallel, global atomics) ----
  for (int i = 0; i < 3; i++){
    zero_k   <<<GRD(V[i]), 256, 0, stream>>>(cntw, V[i]);
    hist_g   <<<GRD(E[i]), 256, 0, stream>>>(rows[i], cntw, E[i]);
    int nb = (V[i] + 1023) / 1024;
    scan_blk <<<nb, 1024, 0, stream>>>(cntw, rp[i], bsum, V[i]);
    scan_top <<<1, 64, 0, stream>>>(bsum, nb);
    scan_add <<<GRD(V[i]), 256, 0, stream>>>(rp[i], rpw, bsum, V[i], E[i]);
    scatter_g<<<GRD(E[i]), 256, 0, stream>>>(rows[i], cols[i], vals[i],
                                             rpw, cs[i], vsf[i], E[i]);
  }

  // ---- level 0 input: [B,V] -> [V,B,1] ----
  transpose_in<<<GRD(BB*V[0]), 256, 0, stream>>>(x_in, NX, V[0]);

  const long OFF_OUT[4] = {0, 12582912, 18874368, 22020096};

  for (int lvl = 0; lvl < 3; lvl++){
    int Vv = V[lvl];
    int Ci = Ci1[lvl], Cm = Co1[lvl];

    // conv1: NX -> BUF0 (bias+ELU fused on last GEMM group)
    long slice1 = (long)Vv*BB*Ci;
    int nf1 = (int)(ARENA_F / slice1); if (nf1 > 9) nf1 = 9;
    run_cheb(NX, ARENA, slice1, nf1, BUF0, w1[lvl], b1[lvl], Vv, Ci, Cm,
             rp[lvl], cs[lvl], vsf[lvl], stream);

    // conv2: BUF0 -> BUF0 (in-place C; Ci==Co so row footprints coincide)
    long slice2 = (long)Vv*BB*Cm;
    int nf2 = (int)(ARENA_F / slice2); if (nf2 > 9) nf2 = 9;
    run_cheb(BUF0, ARENA, slice2, nf2, BUF0, w2[lvl], nullptr, Vv, Cm, Cm,
             rp[lvl], cs[lvl], vsf[lvl], stream);

    long n2 = (long)(Vv/4) * BB * Cm;
    float* pool_out = (lvl == 2) ? (out + OFF_OUT[3]) : (float*)nullptr;
    epilogue_k<<<GRD(n2), 256, 0, stream>>>(BUF0, b2[lvl],
                                            out + OFF_OUT[lvl], NX, pool_out,
                                            Vv, Cm);
  }

  if (out_size != 22806528)
    guard_k<<<1, 64, 0, stream>>>(out, out_size % 4096);
}

// Round 4
// 2296.531 us; speedup vs baseline: 1.5005x; 1.1167x over previous
//
#include <hip/hip_runtime.h>
#include <math.h>

#define BB 8      // batch
#define KCH 10    // Chebyshev order
#define GRD(n) ((int)(((n) + 255) / 256))

typedef __attribute__((ext_vector_type(8))) short bf16x8_t;
typedef __attribute__((ext_vector_type(4))) float f32x4_t;

__device__ __forceinline__ float elu_f(float x){ return x > 0.f ? x : expf(x) - 1.f; }

// float -> bf16 (RNE)
__device__ __forceinline__ unsigned short f2bf(float f){
  unsigned int u = __float_as_uint(f);
  u += 0x7FFFu + ((u >> 16) & 1u);
  return (unsigned short)(u >> 16);
}

// x input is [B, V] fp32 -> x0 [V, B] fp32
__global__ void transpose_in(const float* __restrict__ x, float* __restrict__ x0, int V){
  int i = blockIdx.x*256 + threadIdx.x;
  if (i < BB*V){
    int b = i / V, v = i - b*V;
    x0[(long)v*BB + b] = x[i];
  }
}

// ---------------- CSR build (global atomics) ----------------

__global__ void zero_k(int* __restrict__ p, int n){
  int i = blockIdx.x*256 + threadIdx.x;
  if (i < n) p[i] = 0;
}

__global__ void hist_g(const int* __restrict__ rows, int* __restrict__ cnt, int E){
  int e = blockIdx.x*256 + threadIdx.x;
  if (e < E) atomicAdd(&cnt[rows[e]], 1);
}

__global__ void scan_blk(const int* __restrict__ cnt, int* __restrict__ rp,
                         int* __restrict__ bsum, int V){
  __shared__ int sh[1024];
  int tid = threadIdx.x;
  int i = blockIdx.x*1024 + tid;
  int v = (i < V) ? cnt[i] : 0;
  sh[tid] = v;
  __syncthreads();
  for (int off = 1; off < 1024; off <<= 1){
    int t = (tid >= off) ? sh[tid - off] : 0;
    __syncthreads();
    sh[tid] += t;
    __syncthreads();
  }
  if (i < V) rp[i] = sh[tid] - v;
  if (tid == 1023) bsum[blockIdx.x] = sh[1023];
}

__global__ void scan_top(int* __restrict__ bsum, int nb){
  if (threadIdx.x == 0){
    int run = 0;
    for (int b = 0; b < nb; b++){ int t = bsum[b]; bsum[b] = run; run += t; }
  }
}

__global__ void scan_add(int* __restrict__ rp, int* __restrict__ rpw,
                         const int* __restrict__ bsum, int V, int E){
  int i = blockIdx.x*256 + threadIdx.x;
  if (i < V){
    int v = rp[i] + bsum[i >> 10];
    rp[i] = v;
    rpw[i] = v;
  }
  if (i == 0) rp[V] = E;
}

__global__ void scatter_g(const int* __restrict__ rows, const int* __restrict__ cols,
                          const float* __restrict__ vals,
                          int* __restrict__ rpw, int* __restrict__ cs,
                          float* __restrict__ vs, int E){
  int e = blockIdx.x*256 + threadIdx.x;
  if (e < E){
    int r = rows[e];
    int pos = atomicAdd(&rpw[r], 1);
    if (pos >= 0 && pos < E){
      cs[pos] = cols[e];
      vs[pos] = vals[e];
    }
  }
}

// ---------------- SpMV: float4 row-gather ----------------
__global__ __launch_bounds__(256) void spmv_gather4(
    const int* __restrict__ rp, const int* __restrict__ cs, const float* __restrict__ vs,
    const float4* __restrict__ xin, const float4* __restrict__ xprev,
    float4* __restrict__ xout, int V, int lf4, float alpha, float beta){
  long t = (long)blockIdx.x*256 + threadIdx.x;
  if (t >= ((long)V << lf4)) return;
  int r  = (int)(t >> lf4);
  int f4 = (int)(t - ((long)r << lf4));
  int j0 = rp[r], j1 = rp[r+1];
  float ax = 0.f, ay = 0.f, az = 0.f, aw = 0.f;
  for (int j = j0; j < j1; j++){
    int   c = cs[j];
    float v = vs[j];
    float4 g = xin[((long)c << lf4) + f4];
    ax = fmaf(v, g.x, ax); ay = fmaf(v, g.y, ay);
    az = fmaf(v, g.z, az); aw = fmaf(v, g.w, aw);
  }
  float4 o;
  o.x = alpha*ax; o.y = alpha*ay; o.z = alpha*az; o.w = alpha*aw;
  if (xprev){
    float4 p = xprev[t];
    o.x = fmaf(beta, p.x, o.x); o.y = fmaf(beta, p.y, o.y);
    o.z = fmaf(beta, p.z, o.z); o.w = fmaf(beta, p.w, o.w);
  }
  xout[t] = o;
}

// ---------------- W fragment precompute (bf16 hi/lo, MFMA layout) ----------------
// Frag element (c, ct, lane, i) <- Wcat[c*32 + (lane>>4)*8 + i][ct*16 + (lane&15)]
// stored as short8 at index (c*NCT + ct)*64 + lane. KT = 10*CI (multiple of 32).
__global__ void wfrag_k(const float* __restrict__ w, bf16x8_t* __restrict__ fh,
                        bf16x8_t* __restrict__ fl, int KT, int CO){
  int t = blockIdx.x*256 + threadIdx.x;
  int NCT = CO >> 4;
  int total = (KT >> 5) * NCT * 64;
  if (t >= total) return;
  int lane = t & 63;
  int rest = t >> 6;
  int ct = rest % NCT;
  int c  = rest / NCT;
  int col = ct*16 + (lane & 15);
  int kb  = c*32 + (lane >> 4)*8;
  bf16x8_t h, l;
  #pragma unroll
  for (int i = 0; i < 8; i++){
    float v = w[(long)(kb + i)*CO + col];
    unsigned short hh = f2bf(v);
    float hf = __uint_as_float(((unsigned int)hh) << 16);
    h[i] = (short)hh;
    l[i] = (short)f2bf(v - hf);
  }
  fh[t] = h; fl[t] = l;
}

// ---------------- MFMA GEMM (bf16x2 split, f32 accumulate) ----------------
// C[M,CO] (acc?+=:=) sum_{kk<nk} A_{k0+kk}[M,CI] @ W[k0+kk][CI,CO]
// A_k = (k==0) ? X0 : AR + ((k-1)%nfit)*slice. In-place C==X0 allowed (each
// wave reads only its own 16 rows before writing them; rows disjoint).
template<int CI, int CO>
__global__ __launch_bounds__(256) void gemm_mfma(
    const float* X0, const float* __restrict__ AR,
    const bf16x8_t* __restrict__ fh, const bf16x8_t* __restrict__ fl,
    const float* __restrict__ bias, float* C,
    int k0, int nk, int nfit, long slice, int acc, int do_elu){
  constexpr int NCT = CO/16;   // 16-col tiles
  constexpr int CPS = CI/32;   // k-chunks per slice
  const int lane = threadIdx.x & 63;
  const int wv   = threadIdx.x >> 6;
  const long r0  = ((long)blockIdx.x*4 + wv) * 16;
  const int ra   = lane & 15;        // A row in tile
  const int k8   = (lane >> 4)*8;    // k sub-offset

  f32x4_t accv[NCT];
  #pragma unroll
  for (int ct = 0; ct < NCT; ct++) accv[ct] = (f32x4_t){0.f,0.f,0.f,0.f};

  const int c_off = k0*CPS;
  for (int kk = 0; kk < nk; kk++){
    const int k = k0 + kk;
    const float* Xk = (k == 0) ? X0 : AR + (size_t)((k-1)%nfit)*slice;
    const float* ap = Xk + (r0 + ra)*CI + k8;
    #pragma unroll
    for (int cc = 0; cc < CPS; cc++){
      float4 a0 = *(const float4*)(ap + cc*32);
      float4 a1 = *(const float4*)(ap + cc*32 + 4);
      float av[8] = {a0.x,a0.y,a0.z,a0.w,a1.x,a1.y,a1.z,a1.w};
      bf16x8_t ah, al;
      #pragma unroll
      for (int i = 0; i < 8; i++){
        unsigned short hh = f2bf(av[i]);
        float hf = __uint_as_float(((unsigned int)hh) << 16);
        ah[i] = (short)hh;
        al[i] = (short)f2bf(av[i] - hf);
      }
      const long cb = ((long)(c_off + kk*CPS + cc)*NCT)*64 + lane;
      #pragma unroll
      for (int ct = 0; ct < NCT; ct++){
        bf16x8_t wh = fh[cb + ct*64];
        bf16x8_t wl = fl[cb + ct*64];
        accv[ct] = __builtin_amdgcn_mfma_f32_16x16x32_bf16(ah, wh, accv[ct], 0, 0, 0);
        accv[ct] = __builtin_amdgcn_mfma_f32_16x16x32_bf16(al, wh, accv[ct], 0, 0, 0);
        accv[ct] = __builtin_amdgcn_mfma_f32_16x16x32_bf16(ah, wl, accv[ct], 0, 0, 0);
      }
    }
  }

  // C/D layout: col = lane&15, row = (lane>>4)*4 + j   [m89-verified]
  const int rl  = (lane >> 4)*4;
  const int cb2 = lane & 15;
  #pragma unroll
  for (int ct = 0; ct < NCT; ct++){
    const int col = ct*16 + cb2;
    const float bia = do_elu ? bias[col] : 0.f;
    #pragma unroll
    for (int j = 0; j < 4; j++){
      float* cp = C + (r0 + rl + j)*CO + col;
      float v = accv[ct][j];
      if (acc) v += *cp;
      if (do_elu) v = elu_f(v + bia);
      *cp = v;
    }
  }
}

// ---------------- VALU GEMM for CI==1 (level-0 conv1 only) ----------------
template<int CI, int CO, int RT>
__global__ __launch_bounds__(256) void gemm_multi(
    const float* X0, const float* __restrict__ AR,
    const float* __restrict__ W, const float* __restrict__ bias,
    float* C, int k0, int nk, int nfit, long slice, int acc, int do_elu){
  constexpr int TN = CO/16;
  constexpr int NW = CI*CO;
  extern __shared__ float ws[];

  const int tid = threadIdx.x;
  const int tc = tid & 15, tr = tid >> 4;
  const long r0 = (long)blockIdx.x*(16*RT) + (long)tr*RT;

  const float4* W4 = (const float4*)(W + (size_t)k0*NW);
  for (int i = tid; i < nk*NW/4; i += 256) ((float4*)ws)[i] = W4[i];
  __syncthreads();

  float accv[RT][TN];
  #pragma unroll
  for (int m = 0; m < RT; m++)
    #pragma unroll
    for (int j = 0; j < TN; j++) accv[m][j] = 0.f;

  #pragma unroll 1
  for (int kk = 0; kk < nk; kk++){
    int k = k0 + kk;
    const float* Ak = (k == 0) ? X0 : AR + (size_t)((k-1) % nfit)*slice;
    const float* wsl = ws + (size_t)kk*NW;
    const float* Ar = Ak + r0*CI;
    float am[RT];
    #pragma unroll
    for (int m = 0; m < RT; m += 4){
      float4 a = *(const float4*)(Ar + m);
      am[m] = a.x; am[m+1] = a.y; am[m+2] = a.z; am[m+3] = a.w;
    }
    const float* wr = &wsl[tc];
    #pragma unroll
    for (int j = 0; j < TN; j++){
      float wv = wr[j*16];
      #pragma unroll
      for (int m = 0; m < RT; m++)
        accv[m][j] = fmaf(am[m], wv, accv[m][j]);
    }
  }

  #pragma unroll
  for (int m = 0; m < RT; m++){
    float* Cr = C + (r0 + m)*CO;
    #pragma unroll
    for (int j = 0; j < TN; j++){
      int col = tc + j*16;
      float v = accv[m][j];
      if (acc) v += Cr[col];
      if (do_elu) v = elu_f(v + bias[col]);
      Cr[col] = v;
    }
  }
}

static void launch_gemm(const float* X0, const float* AR,
                        const bf16x8_t* fh, const bf16x8_t* fl,
                        const float* W, const float* bias, float* C,
                        long M, int Ci, int Co, int k0, int nk, int nfit,
                        long slice, int acc, int do_elu, hipStream_t st){
  if (Ci == 1){
    size_t sh = (size_t)nk * 32 * sizeof(float);
    gemm_multi<1,32,8><<<(int)(M/128), 256, sh, st>>>(
        X0, AR, W, bias, C, k0, nk, nfit, slice, acc, do_elu);
    return;
  }
  int grid = (int)(M / 64);
#define GM(ci,co) \
  if (Ci == ci && Co == co){ \
    gemm_mfma<ci,co><<<grid, 256, 0, st>>>( \
        X0, AR, fh, fl, bias, C, k0, nk, nfit, slice, acc, do_elu); \
    return; }
  GM(32,32) GM(32,64) GM(64,64) GM(64,128) GM(128,128)
#undef GM
}

// out2 [V,B,C] pre-bias -> skip (d_out, [B,V,C]), pooled -> nx [V/4,B,C],
// optional pooled -> pool_out (d_out, [B,V/4,C])
__global__ void epilogue_k(const float* __restrict__ out2, const float* __restrict__ bias,
                           float* __restrict__ skip_out, float* __restrict__ nx,
                           float* __restrict__ pool_out, int V, int C){
  long t = (long)blockIdx.x*256 + threadIdx.x;
  long total = (long)(V/4)*BB*C;
  if (t >= total) return;
  int  c  = (int)(t % C);
  long bv = t / C;
  int  b  = (int)(bv % BB);
  int  v2 = (int)(bv / BB);
  float bia = bias[c];
  float s = 0.f;
  for (int j = 0; j < 4; j++){
    long v = (long)4*v2 + j;
    float val = elu_f(out2[(v*BB + b)*C + c] + bia);
    skip_out[((long)b*V + v)*C + c] = val;
    s += val;
  }
  s *= 0.25f;
  nx[((long)v2*BB + b)*C + c] = s;
  if (pool_out) pool_out[((long)b*(V/4) + v2)*C + c] = s;
}

__global__ void guard_k(float* __restrict__ out0, int code){
  if (threadIdx.x == 0) out0[0] = 1.0e6f + (float)code;
}

// ---------------- host driver ----------------

static int ilog2(int x){ int l = 0; while ((1 << l) < x) l++; return l; }

static void run_cheb(const float* x0, float* arena, long slice, int nfit,
                     float* outC, const float* w, const float* bias,
                     const bf16x8_t* fh, const bf16x8_t* fl,
                     int V, int Ci, int Co, const int* rp, const int* cs, const float* vs,
                     hipStream_t stream){
  long M = (long)V*BB;
  int F4 = BB*Ci/4;
  int lf4 = ilog2(F4);
  long n4 = (long)V*F4;

  int k0 = 0;
  int g = (KCH < nfit + 1) ? KCH : nfit + 1;
  int next_k = 1;
  while (k0 < KCH){
    int kend = k0 + g;
    for (int k = next_k; k < kend; k++){
      float* dst = arena + (size_t)((k-1) % nfit)*slice;
      const float* src = (k >= 2) ? arena + (size_t)((k-2) % nfit)*slice : x0;
      const float* prv = (k >= 3) ? arena + (size_t)((k-3) % nfit)*slice
                                  : ((k == 2) ? x0 : nullptr);
      spmv_gather4<<<GRD(n4), 256, 0, stream>>>(rp, cs, vs, (const float4*)src,
                                                (const float4*)prv, (float4*)dst, V, lf4,
                                                (k == 1) ? 1.f : 2.f, (k == 1) ? 0.f : -1.f);
    }
    next_k = kend;
    launch_gemm(x0, arena, fh, fl, w, bias, outC, M, Ci, Co, k0, g, nfit, slice,
                (k0 > 0) ? 1 : 0, (bias && kend == KCH) ? 1 : 0, stream);
    k0 = kend;
    g = (KCH - k0 < nfit) ? (KCH - k0) : nfit;
  }
}

extern "C" void kernel_launch(void* const* d_in, const int* in_sizes, int n_in,
                              void* d_out, int out_size, void* d_ws, size_t ws_size,
                              hipStream_t stream){
  const float* x_in  = (const float*)d_in[0];
  const float* w1[3] = {(const float*)d_in[1], (const float*)d_in[8],  (const float*)d_in[15]};
  const float* b1[3] = {(const float*)d_in[2], (const float*)d_in[9],  (const float*)d_in[16]};
  const float* w2[3] = {(const float*)d_in[3], (const float*)d_in[10], (const float*)d_in[17]};
  const float* b2[3] = {(const float*)d_in[4], (const float*)d_in[11], (const float*)d_in[18]};
  const int*  rows[3]= {(const int*)d_in[5],   (const int*)d_in[12],   (const int*)d_in[19]};
  const int*  cols[3]= {(const int*)d_in[6],   (const int*)d_in[13],   (const int*)d_in[20]};
  const float* vals[3]={(const float*)d_in[7], (const float*)d_in[14], (const float*)d_in[21]};
  float* out = (float*)d_out;

  const int V[3] = {49152, 12288, 3072};
  const int E[3] = {393216, 98304, 24576};
  const int Ci1[3] = {1, 32, 64};
  const int Co1[3] = {32, 64, 128};

  // ---- workspace layout (fp32 units) ----
  float* wsf = (float*)d_ws;
  size_t off = 0;
  const size_t BUFSZ = (size_t)49152 * BB * 32;   // 12,582,912 floats
  float* BUF0 = wsf + off; off += BUFSZ;
  float* ARENA = wsf + off; off += 3*BUFSZ;       // contiguous slice arena
  float* NX   = wsf + off; off += (size_t)12288 * BB * 32;
  int* rp[3]; int* cs[3]; float* vsf[3];
  for (int i = 0; i < 3; i++){
    rp[i]  = (int*)(wsf + off); off += V[i] + 1;
    cs[i]  = (int*)(wsf + off); off += E[i];
    vsf[i] =        wsf + off;  off += E[i];
  }
  int* cntw = (int*)(wsf + off); off += 49152;
  int* bsum = (int*)(wsf + off); off += 64;
  int* rpw  = (int*)(wsf + off); off += 49152;
  off = (off + 3) & ~(size_t)3;                   // 16B-align fragment arena
  bf16x8_t* FR = (bf16x8_t*)(wsf + off);
  // frag sizes (short8 units): w2L0 1280, w1L1 2560, w2L1 5120, w1L2 10240, w2L2 20480
  const long FS[5] = {1280, 2560, 5120, 10240, 20480};
  bf16x8_t *fh_[5], *fl_[5];
  {
    long fo = 0;
    for (int i = 0; i < 5; i++){ fh_[i] = FR + fo; fl_[i] = FR + fo + FS[i]; fo += 2*FS[i]; }
    off += (size_t)(2*(1280+2560+5120+10240+20480)) * 4;   // short8 = 4 floats
  }
  if (ws_size < off * sizeof(float)) return;

  const long ARENA_F = (long)3*BUFSZ;

  // ---- W fragments (hi/lo bf16, MFMA layout) — once per launch ----
  wfrag_k<<<GRD(FS[0]), 256, 0, stream>>>(w2[0], fh_[0], fl_[0],  320,  32);
  wfrag_k<<<GRD(FS[1]), 256, 0, stream>>>(w1[1], fh_[1], fl_[1],  320,  64);
  wfrag_k<<<GRD(FS[2]), 256, 0, stream>>>(w2[1], fh_[2], fl_[2],  640,  64);
  wfrag_k<<<GRD(FS[3]), 256, 0, stream>>>(w1[2], fh_[3], fl_[3],  640, 128);
  wfrag_k<<<GRD(FS[4]), 256, 0, stream>>>(w2[2], fh_[4], fl_[4], 1280, 128);

  // ---- CSR build per level ----
  for (int i = 0; i < 3; i++){
    zero_k   <<<GRD(V[i]), 256, 0, stream>>>(cntw, V[i]);
    hist_g   <<<GRD(E[i]), 256, 0, stream>>>(rows[i], cntw, E[i]);
    int nb = (V[i] + 1023) / 1024;
    scan_blk <<<nb, 1024, 0, stream>>>(cntw, rp[i], bsum, V[i]);
    scan_top <<<1, 64, 0, stream>>>(bsum, nb);
    scan_add <<<GRD(V[i]), 256, 0, stream>>>(rp[i], rpw, bsum, V[i], E[i]);
    scatter_g<<<GRD(E[i]), 256, 0, stream>>>(rows[i], cols[i], vals[i],
                                             rpw, cs[i], vsf[i], E[i]);
  }

  // ---- level 0 input: [B,V] -> [V,B,1] ----
  transpose_in<<<GRD(BB*V[0]), 256, 0, stream>>>(x_in, NX, V[0]);

  const long OFF_OUT[4] = {0, 12582912, 18874368, 22020096};
  const int FH1[3] = {-1, 1, 3};   // frag index for w1 per level (-1 = VALU path)
  const int FH2[3] = { 0, 2, 4};   // frag index for w2 per level

  for (int lvl = 0; lvl < 3; lvl++){
    int Vv = V[lvl];
    int Ci = Ci1[lvl], Cm = Co1[lvl];

    // conv1: NX -> BUF0 (bias+ELU fused on last GEMM group)
    long slice1 = (long)Vv*BB*Ci;
    int nf1 = (int)(ARENA_F / slice1); if (nf1 > 9) nf1 = 9;
    const bf16x8_t* f1h = (FH1[lvl] >= 0) ? fh_[FH1[lvl]] : nullptr;
    const bf16x8_t* f1l = (FH1[lvl] >= 0) ? fl_[FH1[lvl]] : nullptr;
    run_cheb(NX, ARENA, slice1, nf1, BUF0, w1[lvl], b1[lvl], f1h, f1l,
             Vv, Ci, Cm, rp[lvl], cs[lvl], vsf[lvl], stream);

    // conv2: BUF0 -> BUF0 (in-place; per-wave rows disjoint)
    long slice2 = (long)Vv*BB*Cm;
    int nf2 = (int)(ARENA_F / slice2); if (nf2 > 9) nf2 = 9;
    run_cheb(BUF0, ARENA, slice2, nf2, BUF0, w2[lvl], nullptr,
             fh_[FH2[lvl]], fl_[FH2[lvl]],
             Vv, Cm, Cm, rp[lvl], cs[lvl], vsf[lvl], stream);

    long n2 = (long)(Vv/4) * BB * Cm;
    float* pool_out = (lvl == 2) ? (out + OFF_OUT[3]) : (float*)nullptr;
    epilogue_k<<<GRD(n2), 256, 0, stream>>>(BUF0, b2[lvl],
                                            out + OFF_OUT[lvl], NX, pool_out,
                                            Vv, Cm);
  }

  if (out_size != 22806528)
    guard_k<<<1, 64, 0, stream>>>(out, out_size % 4096);
}

// Round 5
// 2278.109 us; speedup vs baseline: 1.5127x; 1.0081x over previous
//
#include <hip/hip_runtime.h>
#include <math.h>

#define BB 8      // batch
#define KCH 10    // Chebyshev order
#define GRD(n) ((int)(((n) + 255) / 256))

typedef __attribute__((ext_vector_type(8))) short bf16x8_t;
typedef __attribute__((ext_vector_type(4))) float f32x4_t;

__device__ __forceinline__ float elu_f(float x){ return x > 0.f ? x : expf(x) - 1.f; }

// float -> bf16 (RNE)
__device__ __forceinline__ unsigned short f2bf(float f){
  unsigned int u = __float_as_uint(f);
  u += 0x7FFFu + ((u >> 16) & 1u);
  return (unsigned short)(u >> 16);
}

// x input is [B, V] fp32 -> x0 [V, B] fp32
__global__ void transpose_in(const float* __restrict__ x, float* __restrict__ x0, int V){
  int i = blockIdx.x*256 + threadIdx.x;
  if (i < BB*V){
    int b = i / V, v = i - b*V;
    x0[(long)v*BB + b] = x[i];
  }
}

// ---------------- CSR build (global atomics) ----------------

__global__ void zero_k(int* __restrict__ p, int n){
  int i = blockIdx.x*256 + threadIdx.x;
  if (i < n) p[i] = 0;
}

__global__ void hist_g(const int* __restrict__ rows, int* __restrict__ cnt, int E){
  int e = blockIdx.x*256 + threadIdx.x;
  if (e < E) atomicAdd(&cnt[rows[e]], 1);
}

__global__ void scan_blk(const int* __restrict__ cnt, int* __restrict__ rp,
                         int* __restrict__ bsum, int V){
  __shared__ int sh[1024];
  int tid = threadIdx.x;
  int i = blockIdx.x*1024 + tid;
  int v = (i < V) ? cnt[i] : 0;
  sh[tid] = v;
  __syncthreads();
  for (int off = 1; off < 1024; off <<= 1){
    int t = (tid >= off) ? sh[tid - off] : 0;
    __syncthreads();
    sh[tid] += t;
    __syncthreads();
  }
  if (i < V) rp[i] = sh[tid] - v;
  if (tid == 1023) bsum[blockIdx.x] = sh[1023];
}

__global__ void scan_top(int* __restrict__ bsum, int nb){
  if (threadIdx.x == 0){
    int run = 0;
    for (int b = 0; b < nb; b++){ int t = bsum[b]; bsum[b] = run; run += t; }
  }
}

__global__ void scan_add(int* __restrict__ rp, int* __restrict__ rpw,
                         const int* __restrict__ bsum, int V, int E){
  int i = blockIdx.x*256 + threadIdx.x;
  if (i < V){
    int v = rp[i] + bsum[i >> 10];
    rp[i] = v;
    rpw[i] = v;
  }
  if (i == 0) rp[V] = E;
}

__global__ void scatter_g(const int* __restrict__ rows, const int* __restrict__ cols,
                          const float* __restrict__ vals,
                          int* __restrict__ rpw, int* __restrict__ cs,
                          float* __restrict__ vs, int E){
  int e = blockIdx.x*256 + threadIdx.x;
  if (e < E){
    int r = rows[e];
    int pos = atomicAdd(&rpw[r], 1);
    if (pos >= 0 && pos < E){
      cs[pos] = cols[e];
      vs[pos] = vals[e];
    }
  }
}

// ---------------- SpMV: float4 row-gather ----------------
__global__ __launch_bounds__(256) void spmv_gather4(
    const int* __restrict__ rp, const int* __restrict__ cs, const float* __restrict__ vs,
    const float4* __restrict__ xin, const float4* __restrict__ xprev,
    float4* __restrict__ xout, int V, int lf4, float alpha, float beta){
  long t = (long)blockIdx.x*256 + threadIdx.x;
  if (t >= ((long)V << lf4)) return;
  int r  = (int)(t >> lf4);
  int f4 = (int)(t - ((long)r << lf4));
  int j0 = rp[r], j1 = rp[r+1];
  float ax = 0.f, ay = 0.f, az = 0.f, aw = 0.f;
  for (int j = j0; j < j1; j++){
    int   c = cs[j];
    float v = vs[j];
    float4 g = xin[((long)c << lf4) + f4];
    ax = fmaf(v, g.x, ax); ay = fmaf(v, g.y, ay);
    az = fmaf(v, g.z, az); aw = fmaf(v, g.w, aw);
  }
  float4 o;
  o.x = alpha*ax; o.y = alpha*ay; o.z = alpha*az; o.w = alpha*aw;
  if (xprev){
    float4 p = xprev[t];
    o.x = fmaf(beta, p.x, o.x); o.y = fmaf(beta, p.y, o.y);
    o.z = fmaf(beta, p.z, o.z); o.w = fmaf(beta, p.w, o.w);
  }
  xout[t] = o;
}

// ---------------- W fragment precompute (bf16 hi/lo, MFMA layout) ----------------
// Frag element (c, ct, lane, i) <- Wcat[c*32 + (lane>>4)*8 + i][ct*16 + (lane&15)]
// stored as short8 at index (c*NCT + ct)*64 + lane. KT = 10*CI (multiple of 32).
__global__ void wfrag_k(const float* __restrict__ w, bf16x8_t* __restrict__ fh,
                        bf16x8_t* __restrict__ fl, int KT, int CO){
  int t = blockIdx.x*256 + threadIdx.x;
  int NCT = CO >> 4;
  int total = (KT >> 5) * NCT * 64;
  if (t >= total) return;
  int lane = t & 63;
  int rest = t >> 6;
  int ct = rest % NCT;
  int c  = rest / NCT;
  int col = ct*16 + (lane & 15);
  int kb  = c*32 + (lane >> 4)*8;
  bf16x8_t h, l;
  #pragma unroll
  for (int i = 0; i < 8; i++){
    float v = w[(long)(kb + i)*CO + col];
    unsigned short hh = f2bf(v);
    float hf = __uint_as_float(((unsigned int)hh) << 16);
    h[i] = (short)hh;
    l[i] = (short)f2bf(v - hf);
  }
  fh[t] = h; fl[t] = l;
}

// ---------------- MFMA GEMM (bf16x2 split, f32 accumulate) ----------------
// C[M,CO] (acc?+=:=) sum_{kk<nk} A_{k0+kk}[M,CI] @ W[k0+kk][CI,CO]
// A_k = (k==0) ? X0 : AR + ((k-1)%nfit)*slice. In-place C==X0 allowed (each
// wave reads only its own rows before writing them; rows disjoint).
// MT 16-row tiles per wave; depth-2 software pipeline over k-chunks.
template<int CI, int CO, int MT, int TPB>
__global__ __launch_bounds__(TPB) void gemm_mfma(
    const float* X0, const float* __restrict__ AR,
    const bf16x8_t* __restrict__ fh, const bf16x8_t* __restrict__ fl,
    const float* __restrict__ bias, float* C,
    int k0, int nk, int nfit, long slice, int acc, int do_elu){
  constexpr int NCT = CO/16;   // 16-col tiles
  constexpr int CPS = CI/32;   // 32-k chunks per slice
  constexpr int WPB = TPB/64;
  const int lane = threadIdx.x & 63;
  const int wv   = threadIdx.x >> 6;
  const long r0  = ((long)blockIdx.x*WPB + wv) * (16*MT);
  const int ra   = lane & 15;        // A row in tile
  const int k8   = (lane >> 4)*8;    // k sub-offset
  const int c_off = k0*CPS;
  const int nch = nk*CPS;

  f32x4_t accv[MT][NCT];
  #pragma unroll
  for (int t = 0; t < MT; t++)
    #pragma unroll
    for (int ct = 0; ct < NCT; ct++) accv[t][ct] = (f32x4_t){0.f,0.f,0.f,0.f};

  float4 Abuf0[MT][2], Abuf1[MT][2];

  auto loadA = [&](int ch, float4 (&A)[MT][2]){
    int kk = ch / CPS;                 // CPS is power of 2 -> shift
    int cc = ch - kk*CPS;
    int k  = k0 + kk;
    const float* Xk = (k == 0) ? X0 : AR + (size_t)((k-1) % nfit)*slice;
    const float* ap = Xk + (long)(r0 + ra)*CI + cc*32 + k8;
    #pragma unroll
    for (int t = 0; t < MT; t++){
      A[t][0] = *(const float4*)(ap + (long)t*16*CI);
      A[t][1] = *(const float4*)(ap + (long)t*16*CI + 4);
    }
  };

  auto computeC = [&](float4 (&A)[MT][2], int ch){
    bf16x8_t ah[MT], al[MT];
    #pragma unroll
    for (int t = 0; t < MT; t++){
      float av[8] = {A[t][0].x, A[t][0].y, A[t][0].z, A[t][0].w,
                     A[t][1].x, A[t][1].y, A[t][1].z, A[t][1].w};
      #pragma unroll
      for (int i = 0; i < 8; i++){
        unsigned short hh = f2bf(av[i]);
        float hf = __uint_as_float(((unsigned int)hh) << 16);
        ah[t][i] = (short)hh;
        al[t][i] = (short)f2bf(av[i] - hf);
      }
    }
    const long cb = ((long)(c_off + ch)*NCT)*64 + lane;
    #pragma unroll
    for (int ct = 0; ct < NCT; ct++){
      bf16x8_t wh = fh[cb + ct*64];
      bf16x8_t wl = fl[cb + ct*64];
      #pragma unroll
      for (int t = 0; t < MT; t++){
        accv[t][ct] = __builtin_amdgcn_mfma_f32_16x16x32_bf16(ah[t], wh, accv[t][ct], 0, 0, 0);
        accv[t][ct] = __builtin_amdgcn_mfma_f32_16x16x32_bf16(al[t], wh, accv[t][ct], 0, 0, 0);
        accv[t][ct] = __builtin_amdgcn_mfma_f32_16x16x32_bf16(ah[t], wl, accv[t][ct], 0, 0, 0);
      }
    }
  };

  loadA(0, Abuf0);
  int ch = 0;
  while (true){
    if (ch + 1 < nch) loadA(ch + 1, Abuf1);
    computeC(Abuf0, ch);
    if (++ch >= nch) break;
    if (ch + 1 < nch) loadA(ch + 1, Abuf0);
    computeC(Abuf1, ch);
    if (++ch >= nch) break;
  }

  // C/D layout: col = lane&15, row = (lane>>4)*4 + j   [m89-verified]
  const int rl  = (lane >> 4)*4;
  const int cb2 = lane & 15;
  #pragma unroll
  for (int t = 0; t < MT; t++){
    #pragma unroll
    for (int ct = 0; ct < NCT; ct++){
      const int col = ct*16 + cb2;
      const float bia = do_elu ? bias[col] : 0.f;
      #pragma unroll
      for (int j = 0; j < 4; j++){
        float* cp = C + (r0 + t*16 + rl + j)*CO + col;
        float v = accv[t][ct][j];
        if (acc) v += *cp;
        if (do_elu) v = elu_f(v + bia);
        *cp = v;
      }
    }
  }
}

// ---------------- VALU GEMM for CI==1 (level-0 conv1 only) ----------------
template<int CI, int CO, int RT>
__global__ __launch_bounds__(256) void gemm_multi(
    const float* X0, const float* __restrict__ AR,
    const float* __restrict__ W, const float* __restrict__ bias,
    float* C, int k0, int nk, int nfit, long slice, int acc, int do_elu){
  constexpr int TN = CO/16;
  constexpr int NW = CI*CO;
  extern __shared__ float ws[];

  const int tid = threadIdx.x;
  const int tc = tid & 15, tr = tid >> 4;
  const long r0 = (long)blockIdx.x*(16*RT) + (long)tr*RT;

  const float4* W4 = (const float4*)(W + (size_t)k0*NW);
  for (int i = tid; i < nk*NW/4; i += 256) ((float4*)ws)[i] = W4[i];
  __syncthreads();

  float accv[RT][TN];
  #pragma unroll
  for (int m = 0; m < RT; m++)
    #pragma unroll
    for (int j = 0; j < TN; j++) accv[m][j] = 0.f;

  #pragma unroll 1
  for (int kk = 0; kk < nk; kk++){
    int k = k0 + kk;
    const float* Ak = (k == 0) ? X0 : AR + (size_t)((k-1) % nfit)*slice;
    const float* wsl = ws + (size_t)kk*NW;
    const float* Ar = Ak + r0*CI;
    float am[RT];
    #pragma unroll
    for (int m = 0; m < RT; m += 4){
      float4 a = *(const float4*)(Ar + m);
      am[m] = a.x; am[m+1] = a.y; am[m+2] = a.z; am[m+3] = a.w;
    }
    const float* wr = &wsl[tc];
    #pragma unroll
    for (int j = 0; j < TN; j++){
      float wv = wr[j*16];
      #pragma unroll
      for (int m = 0; m < RT; m++)
        accv[m][j] = fmaf(am[m], wv, accv[m][j]);
    }
  }

  #pragma unroll
  for (int m = 0; m < RT; m++){
    float* Cr = C + (r0 + m)*CO;
    #pragma unroll
    for (int j = 0; j < TN; j++){
      int col = tc + j*16;
      float v = accv[m][j];
      if (acc) v += Cr[col];
      if (do_elu) v = elu_f(v + bias[col]);
      Cr[col] = v;
    }
  }
}

static void launch_gemm(const float* X0, const float* AR,
                        const bf16x8_t* fh, const bf16x8_t* fl,
                        const float* W, const float* bias, float* C,
                        long M, int Ci, int Co, int k0, int nk, int nfit,
                        long slice, int acc, int do_elu, hipStream_t st){
  if (Ci == 1){
    size_t sh = (size_t)nk * 32 * sizeof(float);
    gemm_multi<1,32,8><<<(int)(M/128), 256, sh, st>>>(
        X0, AR, W, bias, C, k0, nk, nfit, slice, acc, do_elu);
    return;
  }
#define GM(ci,co,mt,tpb) \
  if (Ci == ci && Co == co){ \
    gemm_mfma<ci,co,mt,tpb><<<(int)(M/((tpb/64)*16*mt)), tpb, 0, st>>>( \
        X0, AR, fh, fl, bias, C, k0, nk, nfit, slice, acc, do_elu); \
    return; }
  GM(32,32,2,256) GM(32,64,2,256) GM(64,64,2,256) GM(64,128,1,64) GM(128,128,1,64)
#undef GM
}

// out2 [V,B,C] pre-bias -> skip (d_out, [B,V,C]), pooled -> nx [V/4,B,C],
// optional pooled -> pool_out (d_out, [B,V/4,C])
__global__ void epilogue_k(const float* __restrict__ out2, const float* __restrict__ bias,
                           float* __restrict__ skip_out, float* __restrict__ nx,
                           float* __restrict__ pool_out, int V, int C){
  long t = (long)blockIdx.x*256 + threadIdx.x;
  long total = (long)(V/4)*BB*C;
  if (t >= total) return;
  int  c  = (int)(t % C);
  long bv = t / C;
  int  b  = (int)(bv % BB);
  int  v2 = (int)(bv / BB);
  float bia = bias[c];
  float s = 0.f;
  for (int j = 0; j < 4; j++){
    long v = (long)4*v2 + j;
    float val = elu_f(out2[(v*BB + b)*C + c] + bia);
    skip_out[((long)b*V + v)*C + c] = val;
    s += val;
  }
  s *= 0.25f;
  nx[((long)v2*BB + b)*C + c] = s;
  if (pool_out) pool_out[((long)b*(V/4) + v2)*C + c] = s;
}

__global__ void guard_k(float* __restrict__ out0, int code){
  if (threadIdx.x == 0) out0[0] = 1.0e6f + (float)code;
}

// ---------------- host driver ----------------

static int ilog2(int x){ int l = 0; while ((1 << l) < x) l++; return l; }

static void run_cheb(const float* x0, float* arena, long slice, int nfit,
                     float* outC, const float* w, const float* bias,
                     const bf16x8_t* fh, const bf16x8_t* fl,
                     int V, int Ci, int Co, const int* rp, const int* cs, const float* vs,
                     hipStream_t stream){
  long M = (long)V*BB;
  int F4 = BB*Ci/4;
  int lf4 = ilog2(F4);
  long n4 = (long)V*F4;

  int k0 = 0;
  int g = (KCH < nfit + 1) ? KCH : nfit + 1;
  int next_k = 1;
  while (k0 < KCH){
    int kend = k0 + g;
    for (int k = next_k; k < kend; k++){
      float* dst = arena + (size_t)((k-1) % nfit)*slice;
      const float* src = (k >= 2) ? arena + (size_t)((k-2) % nfit)*slice : x0;
      const float* prv = (k >= 3) ? arena + (size_t)((k-3) % nfit)*slice
                                  : ((k == 2) ? x0 : nullptr);
      spmv_gather4<<<GRD(n4), 256, 0, stream>>>(rp, cs, vs, (const float4*)src,
                                                (const float4*)prv, (float4*)dst, V, lf4,
                                                (k == 1) ? 1.f : 2.f, (k == 1) ? 0.f : -1.f);
    }
    next_k = kend;
    launch_gemm(x0, arena, fh, fl, w, bias, outC, M, Ci, Co, k0, g, nfit, slice,
                (k0 > 0) ? 1 : 0, (bias && kend == KCH) ? 1 : 0, stream);
    k0 = kend;
    g = (KCH - k0 < nfit) ? (KCH - k0) : nfit;
  }
}

extern "C" void kernel_launch(void* const* d_in, const int* in_sizes, int n_in,
                              void* d_out, int out_size, void* d_ws, size_t ws_size,
                              hipStream_t stream){
  const float* x_in  = (const float*)d_in[0];
  const float* w1[3] = {(const float*)d_in[1], (const float*)d_in[8],  (const float*)d_in[15]};
  const float* b1[3] = {(const float*)d_in[2], (const float*)d_in[9],  (const float*)d_in[16]};
  const float* w2[3] = {(const float*)d_in[3], (const float*)d_in[10], (const float*)d_in[17]};
  const float* b2[3] = {(const float*)d_in[4], (const float*)d_in[11], (const float*)d_in[18]};
  const int*  rows[3]= {(const int*)d_in[5],   (const int*)d_in[12],   (const int*)d_in[19]};
  const int*  cols[3]= {(const int*)d_in[6],   (const int*)d_in[13],   (const int*)d_in[20]};
  const float* vals[3]={(const float*)d_in[7], (const float*)d_in[14], (const float*)d_in[21]};
  float* out = (float*)d_out;

  const int V[3] = {49152, 12288, 3072};
  const int E[3] = {393216, 98304, 24576};
  const int Ci1[3] = {1, 32, 64};
  const int Co1[3] = {32, 64, 128};

  // ---- workspace layout (fp32 units) ----
  float* wsf = (float*)d_ws;
  size_t off = 0;
  const size_t BUFSZ = (size_t)49152 * BB * 32;   // 12,582,912 floats
  float* BUF0 = wsf + off; off += BUFSZ;
  float* ARENA = wsf + off; off += 3*BUFSZ;       // contiguous slice arena
  float* NX   = wsf + off; off += (size_t)12288 * BB * 32;
  int* rp[3]; int* cs[3]; float* vsf[3];
  for (int i = 0; i < 3; i++){
    rp[i]  = (int*)(wsf + off); off += V[i] + 1;
    cs[i]  = (int*)(wsf + off); off += E[i];
    vsf[i] =        wsf + off;  off += E[i];
  }
  int* cntw = (int*)(wsf + off); off += 49152;
  int* bsum = (int*)(wsf + off); off += 64;
  int* rpw  = (int*)(wsf + off); off += 49152;
  off = (off + 3) & ~(size_t)3;                   // 16B-align fragment arena
  bf16x8_t* FR = (bf16x8_t*)(wsf + off);
  // frag sizes (short8 units): w2L0 1280, w1L1 2560, w2L1 5120, w1L2 10240, w2L2 20480
  const long FS[5] = {1280, 2560, 5120, 10240, 20480};
  bf16x8_t *fh_[5], *fl_[5];
  {
    long fo = 0;
    for (int i = 0; i < 5; i++){ fh_[i] = FR + fo; fl_[i] = FR + fo + FS[i]; fo += 2*FS[i]; }
    off += (size_t)(2*(1280+2560+5120+10240+20480)) * 4;   // short8 = 4 floats
  }
  if (ws_size < off * sizeof(float)) return;

  const long ARENA_F = (long)3*BUFSZ;

  // ---- W fragments (hi/lo bf16, MFMA layout) — once per launch ----
  wfrag_k<<<GRD(FS[0]), 256, 0, stream>>>(w2[0], fh_[0], fl_[0],  320,  32);
  wfrag_k<<<GRD(FS[1]), 256, 0, stream>>>(w1[1], fh_[1], fl_[1],  320,  64);
  wfrag_k<<<GRD(FS[2]), 256, 0, stream>>>(w2[1], fh_[2], fl_[2],  640,  64);
  wfrag_k<<<GRD(FS[3]), 256, 0, stream>>>(w1[2], fh_[3], fl_[3],  640, 128);
  wfrag_k<<<GRD(FS[4]), 256, 0, stream>>>(w2[2], fh_[4], fl_[4], 1280, 128);

  // ---- CSR build per level ----
  for (int i = 0; i < 3; i++){
    zero_k   <<<GRD(V[i]), 256, 0, stream>>>(cntw, V[i]);
    hist_g   <<<GRD(E[i]), 256, 0, stream>>>(rows[i], cntw, E[i]);
    int nb = (V[i] + 1023) / 1024;
    scan_blk <<<nb, 1024, 0, stream>>>(cntw, rp[i], bsum, V[i]);
    scan_top <<<1, 64, 0, stream>>>(bsum, nb);
    scan_add <<<GRD(V[i]), 256, 0, stream>>>(rp[i], rpw, bsum, V[i], E[i]);
    scatter_g<<<GRD(E[i]), 256, 0, stream>>>(rows[i], cols[i], vals[i],
                                             rpw, cs[i], vsf[i], E[i]);
  }

  // ---- level 0 input: [B,V] -> [V,B,1] ----
  transpose_in<<<GRD(BB*V[0]), 256, 0, stream>>>(x_in, NX, V[0]);

  const long OFF_OUT[4] = {0, 12582912, 18874368, 22020096};
  const int FH1[3] = {-1, 1, 3};   // frag index for w1 per level (-1 = VALU path)
  const int FH2[3] = { 0, 2, 4};   // frag index for w2 per level

  for (int lvl = 0; lvl < 3; lvl++){
    int Vv = V[lvl];
    int Ci = Ci1[lvl], Cm = Co1[lvl];

    // conv1: NX -> BUF0 (bias+ELU fused on last GEMM group)
    long slice1 = (long)Vv*BB*Ci;
    int nf1 = (int)(ARENA_F / slice1); if (nf1 > 9) nf1 = 9;
    const bf16x8_t* f1h = (FH1[lvl] >= 0) ? fh_[FH1[lvl]] : nullptr;
    const bf16x8_t* f1l = (FH1[lvl] >= 0) ? fl_[FH1[lvl]] : nullptr;
    run_cheb(NX, ARENA, slice1, nf1, BUF0, w1[lvl], b1[lvl], f1h, f1l,
             Vv, Ci, Cm, rp[lvl], cs[lvl], vsf[lvl], stream);

    // conv2: BUF0 -> BUF0 (in-place; per-wave rows disjoint)
    long slice2 = (long)Vv*BB*Cm;
    int nf2 = (int)(ARENA_F / slice2); if (nf2 > 9) nf2 = 9;
    run_cheb(BUF0, ARENA, slice2, nf2, BUF0, w2[lvl], nullptr,
             fh_[FH2[lvl]], fl_[FH2[lvl]],
             Vv, Cm, Cm, rp[lvl], cs[lvl], vsf[lvl], stream);

    long n2 = (long)(Vv/4) * BB * Cm;
    float* pool_out = (lvl == 2) ? (out + OFF_OUT[3]) : (float*)nullptr;
    epilogue_k<<<GRD(n2), 256, 0, stream>>>(BUF0, b2[lvl],
                                            out + OFF_OUT[lvl], NX, pool_out,
                                            Vv, Cm);
  }

  if (out_size != 22806528)
    guard_k<<<1, 64, 0, stream>>>(out, out_size % 4096);
}

// Round 6
// 2198.516 us; speedup vs baseline: 1.5674x; 1.0362x over previous
//
#include <hip/hip_runtime.h>
#include <math.h>

#define BB 8      // batch
#define KCH 10    // Chebyshev order
#define GRD(n) ((int)(((n) + 255) / 256))

typedef __attribute__((ext_vector_type(8))) short bf16x8_t;
typedef __attribute__((ext_vector_type(4))) float f32x4_t;

__device__ __forceinline__ float elu_f(float x){ return x > 0.f ? x : expf(x) - 1.f; }

// float -> bf16 (RNE)
__device__ __forceinline__ unsigned short f2bf(float f){
  unsigned int u = __float_as_uint(f);
  u += 0x7FFFu + ((u >> 16) & 1u);
  return (unsigned short)(u >> 16);
}

// x input is [B, V] fp32 -> x0 [V, B] fp32
__global__ void transpose_in(const float* __restrict__ x, float* __restrict__ x0, int V){
  int i = blockIdx.x*256 + threadIdx.x;
  if (i < BB*V){
    int b = i / V, v = i - b*V;
    x0[(long)v*BB + b] = x[i];
  }
}

// ---------------- CSR build (global atomics) ----------------

__global__ void zero_k(int* __restrict__ p, int n){
  int i = blockIdx.x*256 + threadIdx.x;
  if (i < n) p[i] = 0;
}

__global__ void hist_g(const int* __restrict__ rows, int* __restrict__ cnt, int E){
  int e = blockIdx.x*256 + threadIdx.x;
  if (e < E) atomicAdd(&cnt[rows[e]], 1);
}

__global__ void scan_blk(const int* __restrict__ cnt, int* __restrict__ rp,
                         int* __restrict__ bsum, int V){
  __shared__ int sh[1024];
  int tid = threadIdx.x;
  int i = blockIdx.x*1024 + tid;
  int v = (i < V) ? cnt[i] : 0;
  sh[tid] = v;
  __syncthreads();
  for (int off = 1; off < 1024; off <<= 1){
    int t = (tid >= off) ? sh[tid - off] : 0;
    __syncthreads();
    sh[tid] += t;
    __syncthreads();
  }
  if (i < V) rp[i] = sh[tid] - v;
  if (tid == 1023) bsum[blockIdx.x] = sh[1023];
}

__global__ void scan_top(int* __restrict__ bsum, int nb){
  if (threadIdx.x == 0){
    int run = 0;
    for (int b = 0; b < nb; b++){ int t = bsum[b]; bsum[b] = run; run += t; }
  }
}

__global__ void scan_add(int* __restrict__ rp, int* __restrict__ rpw,
                         const int* __restrict__ bsum, int V, int E){
  int i = blockIdx.x*256 + threadIdx.x;
  if (i < V){
    int v = rp[i] + bsum[i >> 10];
    rp[i] = v;
    rpw[i] = v;
  }
  if (i == 0) rp[V] = E;
}

__global__ void scatter_g(const int* __restrict__ rows, const int* __restrict__ cols,
                          const float* __restrict__ vals,
                          int* __restrict__ rpw, int* __restrict__ cs,
                          float* __restrict__ vs, int E){
  int e = blockIdx.x*256 + threadIdx.x;
  if (e < E){
    int r = rows[e];
    int pos = atomicAdd(&rpw[r], 1);
    if (pos >= 0 && pos < E){
      cs[pos] = cols[e];
      vs[pos] = vals[e];
    }
  }
}

// ---------------- SpMV: float4 row-gather ----------------
__global__ __launch_bounds__(256) void spmv_gather4(
    const int* __restrict__ rp, const int* __restrict__ cs, const float* __restrict__ vs,
    const float4* __restrict__ xin, const float4* __restrict__ xprev,
    float4* __restrict__ xout, int V, int lf4, float alpha, float beta){
  long t = (long)blockIdx.x*256 + threadIdx.x;
  if (t >= ((long)V << lf4)) return;
  int r  = (int)(t >> lf4);
  int f4 = (int)(t - ((long)r << lf4));
  int j0 = rp[r], j1 = rp[r+1];
  float ax = 0.f, ay = 0.f, az = 0.f, aw = 0.f;
  for (int j = j0; j < j1; j++){
    int   c = cs[j];
    float v = vs[j];
    float4 g = xin[((long)c << lf4) + f4];
    ax = fmaf(v, g.x, ax); ay = fmaf(v, g.y, ay);
    az = fmaf(v, g.z, az); aw = fmaf(v, g.w, aw);
  }
  float4 o;
  o.x = alpha*ax; o.y = alpha*ay; o.z = alpha*az; o.w = alpha*aw;
  if (xprev){
    float4 p = xprev[t];
    o.x = fmaf(beta, p.x, o.x); o.y = fmaf(beta, p.y, o.y);
    o.z = fmaf(beta, p.z, o.z); o.w = fmaf(beta, p.w, o.w);
  }
  xout[t] = o;
}

// ---------------- W fragment precompute (bf16 hi/lo, MFMA layout) ----------------
// Frag element (c, ct, lane, i) <- Wcat[c*32 + (lane>>4)*8 + i][ct*16 + (lane&15)]
// stored as short8 at index (c*NCT + ct)*64 + lane. KT = 10*CI (multiple of 32).
__global__ void wfrag_k(const float* __restrict__ w, bf16x8_t* __restrict__ fh,
                        bf16x8_t* __restrict__ fl, int KT, int CO){
  int t = blockIdx.x*256 + threadIdx.x;
  int NCT = CO >> 4;
  int total = (KT >> 5) * NCT * 64;
  if (t >= total) return;
  int lane = t & 63;
  int rest = t >> 6;
  int ct = rest % NCT;
  int c  = rest / NCT;
  int col = ct*16 + (lane & 15);
  int kb  = c*32 + (lane >> 4)*8;
  bf16x8_t h, l;
  #pragma unroll
  for (int i = 0; i < 8; i++){
    float v = w[(long)(kb + i)*CO + col];
    unsigned short hh = f2bf(v);
    float hf = __uint_as_float(((unsigned int)hh) << 16);
    h[i] = (short)hh;
    l[i] = (short)f2bf(v - hf);
  }
  fh[t] = h; fl[t] = l;
}

// ---------------- MFMA GEMM, k-split across 4 waves (small-M shapes) --------
// One 16-row tile per block; wave wv computes a contiguous quarter of the
// k-chunks into register partials; LDS reduce [KW][NCT][4][64] (conflict-free);
// wave wv finalizes NCT/KW column-tiles. In-place C==X0 safe: all A reads
// precede the barrier, writes follow; blocks own disjoint rows.
template<int CI, int CO, int KW>
__global__ __launch_bounds__(KW*64) void gemm_mfma_ks(
    const float* X0, const float* __restrict__ AR,
    const bf16x8_t* __restrict__ fh, const bf16x8_t* __restrict__ fl,
    const float* __restrict__ bias, float* C,
    int k0, int nk, int nfit, long slice, int acc, int do_elu){
  constexpr int NCT = CO/16;
  constexpr int CPS = CI/32;
  __shared__ float red[KW][NCT][4][64];
  const int lane = threadIdx.x & 63;
  const int wv   = threadIdx.x >> 6;
  const long r0  = (long)blockIdx.x * 16;
  const int ra   = lane & 15;
  const int k8   = (lane >> 4)*8;
  const int c_off = k0*CPS;
  const int nch  = nk*CPS;
  const int c0 = (wv*nch)/KW, c1 = ((wv+1)*nch)/KW;

  f32x4_t accv[NCT];
  #pragma unroll
  for (int ct = 0; ct < NCT; ct++) accv[ct] = (f32x4_t){0.f,0.f,0.f,0.f};

  float4 A0[2], A1[2];
  auto loadA = [&](int ch, float4 (&A)[2]){
    int kk = ch / CPS;
    int cc = ch - kk*CPS;
    int k  = k0 + kk;
    const float* Xk = (k == 0) ? X0 : AR + (size_t)((k-1) % nfit)*slice;
    const float* ap = Xk + (long)(r0 + ra)*CI + cc*32 + k8;
    A[0] = *(const float4*)(ap);
    A[1] = *(const float4*)(ap + 4);
  };
  auto computeC = [&](float4 (&A)[2], int ch){
    float av[8] = {A[0].x, A[0].y, A[0].z, A[0].w, A[1].x, A[1].y, A[1].z, A[1].w};
    bf16x8_t ah, al;
    #pragma unroll
    for (int i = 0; i < 8; i++){
      unsigned short hh = f2bf(av[i]);
      float hf = __uint_as_float(((unsigned int)hh) << 16);
      ah[i] = (short)hh;
      al[i] = (short)f2bf(av[i] - hf);
    }
    const long cb = ((long)(c_off + ch)*NCT)*64 + lane;
    #pragma unroll
    for (int ct = 0; ct < NCT; ct++){
      bf16x8_t wh = fh[cb + ct*64];
      bf16x8_t wl = fl[cb + ct*64];
      accv[ct] = __builtin_amdgcn_mfma_f32_16x16x32_bf16(ah, wh, accv[ct], 0, 0, 0);
      accv[ct] = __builtin_amdgcn_mfma_f32_16x16x32_bf16(al, wh, accv[ct], 0, 0, 0);
      accv[ct] = __builtin_amdgcn_mfma_f32_16x16x32_bf16(ah, wl, accv[ct], 0, 0, 0);
    }
  };

  if (c0 < c1){
    loadA(c0, A0);
    int ch = c0;
    while (true){
      if (ch + 1 < c1) loadA(ch + 1, A1);
      computeC(A0, ch);
      if (++ch >= c1) break;
      if (ch + 1 < c1) loadA(ch + 1, A0);
      computeC(A1, ch);
      if (++ch >= c1) break;
    }
  }

  #pragma unroll
  for (int ct = 0; ct < NCT; ct++)
    #pragma unroll
    for (int j = 0; j < 4; j++)
      red[wv][ct][j][lane] = accv[ct][j];
  __syncthreads();

  // C/D layout: col = lane&15, row = (lane>>4)*4 + j   [m89-verified]
  const int rl  = (lane >> 4)*4;
  const int cb2 = lane & 15;
  constexpr int CTW = NCT/KW;   // col-tiles per wave in epilogue
  #pragma unroll
  for (int t = 0; t < CTW; t++){
    const int ct  = wv*CTW + t;
    const int col = ct*16 + cb2;
    const float bia = do_elu ? bias[col] : 0.f;
    #pragma unroll
    for (int j = 0; j < 4; j++){
      float v = red[0][ct][j][lane];
      #pragma unroll
      for (int w = 1; w < KW; w++) v += red[w][ct][j][lane];
      float* cp = C + (r0 + rl + j)*CO + col;
      if (acc) v += *cp;
      if (do_elu) v = elu_f(v + bia);
      *cp = v;
    }
  }
}

// ---------------- MFMA GEMM, independent tiles (large-M shapes) ----------------
template<int CI, int CO, int MT, int TPB>
__global__ __launch_bounds__(TPB) void gemm_mfma(
    const float* X0, const float* __restrict__ AR,
    const bf16x8_t* __restrict__ fh, const bf16x8_t* __restrict__ fl,
    const float* __restrict__ bias, float* C,
    int k0, int nk, int nfit, long slice, int acc, int do_elu){
  constexpr int NCT = CO/16;
  constexpr int CPS = CI/32;
  constexpr int WPB = TPB/64;
  const int lane = threadIdx.x & 63;
  const int wv   = threadIdx.x >> 6;
  const long r0  = ((long)blockIdx.x*WPB + wv) * (16*MT);
  const int ra   = lane & 15;
  const int k8   = (lane >> 4)*8;
  const int c_off = k0*CPS;
  const int nch = nk*CPS;

  f32x4_t accv[MT][NCT];
  #pragma unroll
  for (int t = 0; t < MT; t++)
    #pragma unroll
    for (int ct = 0; ct < NCT; ct++) accv[t][ct] = (f32x4_t){0.f,0.f,0.f,0.f};

  float4 Abuf0[MT][2], Abuf1[MT][2];

  auto loadA = [&](int ch, float4 (&A)[MT][2]){
    int kk = ch / CPS;
    int cc = ch - kk*CPS;
    int k  = k0 + kk;
    const float* Xk = (k == 0) ? X0 : AR + (size_t)((k-1) % nfit)*slice;
    const float* ap = Xk + (long)(r0 + ra)*CI + cc*32 + k8;
    #pragma unroll
    for (int t = 0; t < MT; t++){
      A[t][0] = *(const float4*)(ap + (long)t*16*CI);
      A[t][1] = *(const float4*)(ap + (long)t*16*CI + 4);
    }
  };

  auto computeC = [&](float4 (&A)[MT][2], int ch){
    bf16x8_t ah[MT], al[MT];
    #pragma unroll
    for (int t = 0; t < MT; t++){
      float av[8] = {A[t][0].x, A[t][0].y, A[t][0].z, A[t][0].w,
                     A[t][1].x, A[t][1].y, A[t][1].z, A[t][1].w};
      #pragma unroll
      for (int i = 0; i < 8; i++){
        unsigned short hh = f2bf(av[i]);
        float hf = __uint_as_float(((unsigned int)hh) << 16);
        ah[t][i] = (short)hh;
        al[t][i] = (short)f2bf(av[i] - hf);
      }
    }
    const long cb = ((long)(c_off + ch)*NCT)*64 + lane;
    #pragma unroll
    for (int ct = 0; ct < NCT; ct++){
      bf16x8_t wh = fh[cb + ct*64];
      bf16x8_t wl = fl[cb + ct*64];
      #pragma unroll
      for (int t = 0; t < MT; t++){
        accv[t][ct] = __builtin_amdgcn_mfma_f32_16x16x32_bf16(ah[t], wh, accv[t][ct], 0, 0, 0);
        accv[t][ct] = __builtin_amdgcn_mfma_f32_16x16x32_bf16(al[t], wh, accv[t][ct], 0, 0, 0);
        accv[t][ct] = __builtin_amdgcn_mfma_f32_16x16x32_bf16(ah[t], wl, accv[t][ct], 0, 0, 0);
      }
    }
  };

  loadA(0, Abuf0);
  int ch = 0;
  while (true){
    if (ch + 1 < nch) loadA(ch + 1, Abuf1);
    computeC(Abuf0, ch);
    if (++ch >= nch) break;
    if (ch + 1 < nch) loadA(ch + 1, Abuf0);
    computeC(Abuf1, ch);
    if (++ch >= nch) break;
  }

  const int rl  = (lane >> 4)*4;
  const int cb2 = lane & 15;
  #pragma unroll
  for (int t = 0; t < MT; t++){
    #pragma unroll
    for (int ct = 0; ct < NCT; ct++){
      const int col = ct*16 + cb2;
      const float bia = do_elu ? bias[col] : 0.f;
      #pragma unroll
      for (int j = 0; j < 4; j++){
        float* cp = C + (r0 + t*16 + rl + j)*CO + col;
        float v = accv[t][ct][j];
        if (acc) v += *cp;
        if (do_elu) v = elu_f(v + bia);
        *cp = v;
      }
    }
  }
}

// ---------------- VALU GEMM for CI==1 (level-0 conv1 only) ----------------
template<int CI, int CO, int RT>
__global__ __launch_bounds__(256) void gemm_multi(
    const float* X0, const float* __restrict__ AR,
    const float* __restrict__ W, const float* __restrict__ bias,
    float* C, int k0, int nk, int nfit, long slice, int acc, int do_elu){
  constexpr int TN = CO/16;
  constexpr int NW = CI*CO;
  extern __shared__ float ws[];

  const int tid = threadIdx.x;
  const int tc = tid & 15, tr = tid >> 4;
  const long r0 = (long)blockIdx.x*(16*RT) + (long)tr*RT;

  const float4* W4 = (const float4*)(W + (size_t)k0*NW);
  for (int i = tid; i < nk*NW/4; i += 256) ((float4*)ws)[i] = W4[i];
  __syncthreads();

  float accv[RT][TN];
  #pragma unroll
  for (int m = 0; m < RT; m++)
    #pragma unroll
    for (int j = 0; j < TN; j++) accv[m][j] = 0.f;

  #pragma unroll 1
  for (int kk = 0; kk < nk; kk++){
    int k = k0 + kk;
    const float* Ak = (k == 0) ? X0 : AR + (size_t)((k-1) % nfit)*slice;
    const float* wsl = ws + (size_t)kk*NW;
    const float* Ar = Ak + r0*CI;
    float am[RT];
    #pragma unroll
    for (int m = 0; m < RT; m += 4){
      float4 a = *(const float4*)(Ar + m);
      am[m] = a.x; am[m+1] = a.y; am[m+2] = a.z; am[m+3] = a.w;
    }
    const float* wr = &wsl[tc];
    #pragma unroll
    for (int j = 0; j < TN; j++){
      float wv = wr[j*16];
      #pragma unroll
      for (int m = 0; m < RT; m++)
        accv[m][j] = fmaf(am[m], wv, accv[m][j]);
    }
  }

  #pragma unroll
  for (int m = 0; m < RT; m++){
    float* Cr = C + (r0 + m)*CO;
    #pragma unroll
    for (int j = 0; j < TN; j++){
      int col = tc + j*16;
      float v = accv[m][j];
      if (acc) v += Cr[col];
      if (do_elu) v = elu_f(v + bias[col]);
      Cr[col] = v;
    }
  }
}

static void launch_gemm(const float* X0, const float* AR,
                        const bf16x8_t* fh, const bf16x8_t* fl,
                        const float* W, const float* bias, float* C,
                        long M, int Ci, int Co, int k0, int nk, int nfit,
                        long slice, int acc, int do_elu, hipStream_t st){
  if (Ci == 1){
    size_t sh = (size_t)nk * 32 * sizeof(float);
    gemm_multi<1,32,8><<<(int)(M/128), 256, sh, st>>>(
        X0, AR, W, bias, C, k0, nk, nfit, slice, acc, do_elu);
    return;
  }
  // large-M shape: independent 4-wave tiles
  if (Ci == 32 && Co == 32){
    gemm_mfma<32,32,2,256><<<(int)(M/128), 256, 0, st>>>(
        X0, AR, fh, fl, bias, C, k0, nk, nfit, slice, acc, do_elu);
    return;
  }
  // small-M shapes: k-split across 4 waves, one 16-row tile per block
#define GK(ci,co) \
  if (Ci == ci && Co == co){ \
    gemm_mfma_ks<ci,co,4><<<(int)(M/16), 256, 0, st>>>( \
        X0, AR, fh, fl, bias, C, k0, nk, nfit, slice, acc, do_elu); \
    return; }
  GK(32,64) GK(64,64) GK(64,128) GK(128,128)
#undef GK
}

// out2 [V,B,C] pre-bias -> skip (d_out, [B,V,C]), pooled -> nx [V/4,B,C],
// optional pooled -> pool_out (d_out, [B,V/4,C])
__global__ void epilogue_k(const float* __restrict__ out2, const float* __restrict__ bias,
                           float* __restrict__ skip_out, float* __restrict__ nx,
                           float* __restrict__ pool_out, int V, int C){
  long t = (long)blockIdx.x*256 + threadIdx.x;
  long total = (long)(V/4)*BB*C;
  if (t >= total) return;
  int  c  = (int)(t % C);
  long bv = t / C;
  int  b  = (int)(bv % BB);
  int  v2 = (int)(bv / BB);
  float bia = bias[c];
  float s = 0.f;
  for (int j = 0; j < 4; j++){
    long v = (long)4*v2 + j;
    float val = elu_f(out2[(v*BB + b)*C + c] + bia);
    skip_out[((long)b*V + v)*C + c] = val;
    s += val;
  }
  s *= 0.25f;
  nx[((long)v2*BB + b)*C + c] = s;
  if (pool_out) pool_out[((long)b*(V/4) + v2)*C + c] = s;
}

__global__ void guard_k(float* __restrict__ out0, int code){
  if (threadIdx.x == 0) out0[0] = 1.0e6f + (float)code;
}

// ---------------- host driver ----------------

static int ilog2(int x){ int l = 0; while ((1 << l) < x) l++; return l; }

static void run_cheb(const float* x0, float* arena, long slice, int nfit,
                     float* outC, const float* w, const float* bias,
                     const bf16x8_t* fh, const bf16x8_t* fl,
                     int V, int Ci, int Co, const int* rp, const int* cs, const float* vs,
                     hipStream_t stream){
  long M = (long)V*BB;
  int F4 = BB*Ci/4;
  int lf4 = ilog2(F4);
  long n4 = (long)V*F4;

  int k0 = 0;
  int g = (KCH < nfit + 1) ? KCH : nfit + 1;
  int next_k = 1;
  while (k0 < KCH){
    int kend = k0 + g;
    for (int k = next_k; k < kend; k++){
      float* dst = arena + (size_t)((k-1) % nfit)*slice;
      const float* src = (k >= 2) ? arena + (size_t)((k-2) % nfit)*slice : x0;
      const float* prv = (k >= 3) ? arena + (size_t)((k-3) % nfit)*slice
                                  : ((k == 2) ? x0 : nullptr);
      spmv_gather4<<<GRD(n4), 256, 0, stream>>>(rp, cs, vs, (const float4*)src,
                                                (const float4*)prv, (float4*)dst, V, lf4,
                                                (k == 1) ? 1.f : 2.f, (k == 1) ? 0.f : -1.f);
    }
    next_k = kend;
    launch_gemm(x0, arena, fh, fl, w, bias, outC, M, Ci, Co, k0, g, nfit, slice,
                (k0 > 0) ? 1 : 0, (bias && kend == KCH) ? 1 : 0, stream);
    k0 = kend;
    g = (KCH - k0 < nfit) ? (KCH - k0) : nfit;
  }
}

extern "C" void kernel_launch(void* const* d_in, const int* in_sizes, int n_in,
                              void* d_out, int out_size, void* d_ws, size_t ws_size,
                              hipStream_t stream){
  const float* x_in  = (const float*)d_in[0];
  const float* w1[3] = {(const float*)d_in[1], (const float*)d_in[8],  (const float*)d_in[15]};
  const float* b1[3] = {(const float*)d_in[2], (const float*)d_in[9],  (const float*)d_in[16]};
  const float* w2[3] = {(const float*)d_in[3], (const float*)d_in[10], (const float*)d_in[17]};
  const float* b2[3] = {(const float*)d_in[4], (const float*)d_in[11], (const float*)d_in[18]};
  const int*  rows[3]= {(const int*)d_in[5],   (const int*)d_in[12],   (const int*)d_in[19]};
  const int*  cols[3]= {(const int*)d_in[6],   (const int*)d_in[13],   (const int*)d_in[20]};
  const float* vals[3]={(const float*)d_in[7], (const float*)d_in[14], (const float*)d_in[21]};
  float* out = (float*)d_out;

  const int V[3] = {49152, 12288, 3072};
  const int E[3] = {393216, 98304, 24576};
  const int Ci1[3] = {1, 32, 64};
  const int Co1[3] = {32, 64, 128};

  // ---- workspace layout (fp32 units) ----
  float* wsf = (float*)d_ws;
  size_t off = 0;
  const size_t BUFSZ = (size_t)49152 * BB * 32;   // 12,582,912 floats
  float* BUF0 = wsf + off; off += BUFSZ;
  float* ARENA = wsf + off; off += 3*BUFSZ;       // contiguous slice arena
  float* NX   = wsf + off; off += (size_t)12288 * BB * 32;
  int* rp[3]; int* cs[3]; float* vsf[3];
  for (int i = 0; i < 3; i++){
    rp[i]  = (int*)(wsf + off); off += V[i] + 1;
    cs[i]  = (int*)(wsf + off); off += E[i];
    vsf[i] =        wsf + off;  off += E[i];
  }
  int* cntw = (int*)(wsf + off); off += 49152;
  int* bsum = (int*)(wsf + off); off += 64;
  int* rpw  = (int*)(wsf + off); off += 49152;
  off = (off + 3) & ~(size_t)3;                   // 16B-align fragment arena
  bf16x8_t* FR = (bf16x8_t*)(wsf + off);
  // frag sizes (short8 units): w2L0 1280, w1L1 2560, w2L1 5120, w1L2 10240, w2L2 20480
  const long FS[5] = {1280, 2560, 5120, 10240, 20480};
  bf16x8_t *fh_[5], *fl_[5];
  {
    long fo = 0;
    for (int i = 0; i < 5; i++){ fh_[i] = FR + fo; fl_[i] = FR + fo + FS[i]; fo += 2*FS[i]; }
    off += (size_t)(2*(1280+2560+5120+10240+20480)) * 4;   // short8 = 4 floats
  }
  if (ws_size < off * sizeof(float)) return;

  const long ARENA_F = (long)3*BUFSZ;

  // ---- W fragments (hi/lo bf16, MFMA layout) — once per launch ----
  wfrag_k<<<GRD(FS[0]), 256, 0, stream>>>(w2[0], fh_[0], fl_[0],  320,  32);
  wfrag_k<<<GRD(FS[1]), 256, 0, stream>>>(w1[1], fh_[1], fl_[1],  320,  64);
  wfrag_k<<<GRD(FS[2]), 256, 0, stream>>>(w2[1], fh_[2], fl_[2],  640,  64);
  wfrag_k<<<GRD(FS[3]), 256, 0, stream>>>(w1[2], fh_[3], fl_[3],  640, 128);
  wfrag_k<<<GRD(FS[4]), 256, 0, stream>>>(w2[2], fh_[4], fl_[4], 1280, 128);

  // ---- CSR build per level ----
  for (int i = 0; i < 3; i++){
    zero_k   <<<GRD(V[i]), 256, 0, stream>>>(cntw, V[i]);
    hist_g   <<<GRD(E[i]), 256, 0, stream>>>(rows[i], cntw, E[i]);
    int nb = (V[i] + 1023) / 1024;
    scan_blk <<<nb, 1024, 0, stream>>>(cntw, rp[i], bsum, V[i]);
    scan_top <<<1, 64, 0, stream>>>(bsum, nb);
    scan_add <<<GRD(V[i]), 256, 0, stream>>>(rp[i], rpw, bsum, V[i], E[i]);
    scatter_g<<<GRD(E[i]), 256, 0, stream>>>(rows[i], cols[i], vals[i],
                                             rpw, cs[i], vsf[i], E[i]);
  }

  // ---- level 0 input: [B,V] -> [V,B,1] ----
  transpose_in<<<GRD(BB*V[0]), 256, 0, stream>>>(x_in, NX, V[0]);

  const long OFF_OUT[4] = {0, 12582912, 18874368, 22020096};
  const int FH1[3] = {-1, 1, 3};   // frag index for w1 per level (-1 = VALU path)
  const int FH2[3] = { 0, 2, 4};   // frag index for w2 per level

  for (int lvl = 0; lvl < 3; lvl++){
    int Vv = V[lvl];
    int Ci = Ci1[lvl], Cm = Co1[lvl];

    // conv1: NX -> BUF0 (bias+ELU fused on last GEMM group)
    long slice1 = (long)Vv*BB*Ci;
    int nf1 = (int)(ARENA_F / slice1); if (nf1 > 9) nf1 = 9;
    const bf16x8_t* f1h = (FH1[lvl] >= 0) ? fh_[FH1[lvl]] : nullptr;
    const bf16x8_t* f1l = (FH1[lvl] >= 0) ? fl_[FH1[lvl]] : nullptr;
    run_cheb(NX, ARENA, slice1, nf1, BUF0, w1[lvl], b1[lvl], f1h, f1l,
             Vv, Ci, Cm, rp[lvl], cs[lvl], vsf[lvl], stream);

    // conv2: BUF0 -> BUF0 (in-place; per-block rows disjoint)
    long slice2 = (long)Vv*BB*Cm;
    int nf2 = (int)(ARENA_F / slice2); if (nf2 > 9) nf2 = 9;
    run_cheb(BUF0, ARENA, slice2, nf2, BUF0, w2[lvl], nullptr,
             fh_[FH2[lvl]], fl_[FH2[lvl]],
             Vv, Cm, Cm, rp[lvl], cs[lvl], vsf[lvl], stream);

    long n2 = (long)(Vv/4) * BB * Cm;
    float* pool_out = (lvl == 2) ? (out + OFF_OUT[3]) : (float*)nullptr;
    epilogue_k<<<GRD(n2), 256, 0, stream>>>(BUF0, b2[lvl],
                                            out + OFF_OUT[lvl], NX, pool_out,
                                            Vv, Cm);
  }

  if (out_size != 22806528)
    guard_k<<<1, 64, 0, stream>>>(out, out_size % 4096);
}